// Round 8
// baseline (195.719 us; speedup 1.0000x reference)
//
#include <hip/hip_runtime.h>
#include <cstdint>

#define DIM   128
#define KNN   16
#define NB    2
#define NQ    8192
#define NPTS  4096
#define KVROWS 16
#define GRID  32
#define NCELL (GRID*GRID)
#define CAP   384

typedef unsigned short ushort_t;
typedef short vshort8 __attribute__((ext_vector_type(8)));
typedef float vfloat4 __attribute__((ext_vector_type(4)));

__device__ __forceinline__ ushort_t bf16_rne(float f) {
    unsigned u = __float_as_uint(f);
    unsigned r = u + 0x7FFFu + ((u >> 16) & 1u);
    return (ushort_t)(r >> 16);
}
__device__ __forceinline__ int cell_of(float x) {
    int c = (int)(x * 32.0f);
    return min(max(c, 0), GRID - 1);
}

// ---------------- W-products: Wk1 = w_ks@g_w1 ; pwc = [pe_w@g_w1 | pe_w] (64x256, rows 33..63 zero) ----------------
__global__ __launch_bounds__(128) void wprod_k(
    const float* __restrict__ w_ks, const float* __restrict__ g_w1,
    const float* __restrict__ pe_w,
    float* __restrict__ Wk1, float* __restrict__ pwc)
{
    int f = threadIdx.x; int blk = blockIdx.x;
    if (blk < 128) {
        float acc = 0.f;
        for (int t = 0; t < 128; ++t) acc = fmaf(w_ks[blk*128 + t], g_w1[t*128 + f], acc);
        Wk1[blk*128 + f] = acc;
    } else {
        int r = blk - 128;                      // 0..63
        for (int h = 0; h < 2; ++h) {
            int col = f + h*128;
            float v = 0.f;
            if (r < 33) {
                if (col < 128) {
                    float a = 0.f;
                    for (int t = 0; t < 128; ++t) a = fmaf(pe_w[r*128 + t], g_w1[t*128 + col], a);
                    v = a;
                } else {
                    v = pe_w[r*128 + (col - 128)];
                }
            }
            pwc[r*256 + col] = v;
        }
    }
}

// ---------------- pack f32 [K][ncols] into MFMA B-fragments, single bf16 ----------------
// dst layout: [n(NT)][s(KS)][lane(64)][8]; element (lane,i): k=s*32+(lane>>4)*8+i, col=n*16+(lane&15)
__global__ __launch_bounds__(256) void pack_k(
    const float* __restrict__ src, int K, int ncols, int NT, int KS,
    ushort_t* __restrict__ dst)
{
    int gid = blockIdx.x*256 + threadIdx.x;
    int total = NT*KS*64;
    if (gid >= total) return;
    int lane = gid & 63; int c = gid >> 6;
    int s = c % KS; int n = c / KS;
    int k0 = s*32 + ((lane >> 4) << 3);
    int col = n*16 + (lane & 15);
    vshort8 v;
    #pragma unroll
    for (int i = 0; i < 8; ++i) {
        int k = k0 + i;
        float f = (k < K) ? src[k*ncols + col] : 0.f;
        v[i] = (short)bf16_rne(f);
    }
    *(vshort8*)(dst + gid*8) = v;
}

// ---------------- per-batch global branch ----------------
__global__ __launch_bounds__(256) void prep_global_k(
    const float* __restrict__ lat, const float* __restrict__ w_qs,
    const float* __restrict__ w_kg, const float* __restrict__ w_vg,
    const float* __restrict__ g_w1, const float* __restrict__ g_b1,
    const float* __restrict__ g_w2, const float* __restrict__ pe_b,
    float* __restrict__ c1_out, float* __restrict__ vg_out, float* __restrict__ h2g_out)
{
    __shared__ float qs[NB][DIM];
    __shared__ float hg[NB][DIM];
    __shared__ float h1g[NB][DIM];
    int t = threadIdx.x; int b = t >> 7; int f = t & 127;
    float aq = 0.f, ak = 0.f, av = 0.f;
    for (int c = 0; c < DIM; ++c) {
        float l = lat[b*DIM + c];
        aq = fmaf(l, w_qs[c*DIM + f], aq);
        ak = fmaf(l, w_kg[c*DIM + f], ak);
        av = fmaf(l, w_vg[c*DIM + f], av);
    }
    vg_out[b*DIM + f] = av;
    qs[b][f] = aq + pe_b[f];
    hg[b][f] = aq - ak;
    __syncthreads();
    float acc = g_b1[f], acch = g_b1[f];
    for (int c = 0; c < DIM; ++c) {
        float w = g_w1[c*DIM + f];
        acc  = fmaf(qs[b][c], w, acc);
        acch = fmaf(hg[b][c], w, acch);
    }
    c1_out[b*DIM + f] = acc;
    h1g[b][f] = fmaxf(acch, 0.f);
    __syncthreads();
    float acc2 = 0.f;                       // b2 dropped (softmax-invariant)
    for (int c = 0; c < DIM; ++c) acc2 = fmaf(h1g[b][c], g_w2[c*DIM + f], acc2);
    h2g_out[b*DIM + f] = acc2;
}

// ---------------- K1c = c1 - points@Wk1 ; Vp' = points@w_vs + pe_b ----------------
__global__ __launch_bounds__(256) void kv_proj_k(
    const float* __restrict__ points, const float* __restrict__ Wk1,
    const float* __restrict__ w_vs, const float* __restrict__ pe_b,
    const float* __restrict__ c1_,
    float* __restrict__ K1c, float* __restrict__ Vp)
{
    __shared__ __align__(16) float pts[KVROWS*DIM];
    int t = threadIdx.x;
    int r0 = blockIdx.x * KVROWS;
    int b = r0 >> 12;
    #pragma unroll
    for (int k = 0; k < KVROWS*DIM/256; ++k) {
        int e = t + k*256;
        pts[e] = points[r0*DIM + e];
    }
    __syncthreads();
    int f = t & 127; int mat = t >> 7;
    const float* W = mat ? w_vs : Wk1;
    float* O = mat ? Vp : K1c;
    float addv = mat ? pe_b[f] : c1_[b*DIM + f];
    float sgn  = mat ? 1.f : -1.f;
    float acc[KVROWS];
    #pragma unroll
    for (int r = 0; r < KVROWS; ++r) acc[r] = 0.f;
    const float4* pts4 = reinterpret_cast<const float4*>(pts);
    for (int c4 = 0; c4 < DIM/4; ++c4) {
        float w0 = W[(c4*4+0)*DIM + f];
        float w1 = W[(c4*4+1)*DIM + f];
        float w2 = W[(c4*4+2)*DIM + f];
        float w3 = W[(c4*4+3)*DIM + f];
        #pragma unroll
        for (int r = 0; r < KVROWS; ++r) {
            float4 p = pts4[r*(DIM/4) + c4];
            acc[r] = fmaf(p.x, w0, acc[r]);
            acc[r] = fmaf(p.y, w1, acc[r]);
            acc[r] = fmaf(p.z, w2, acc[r]);
            acc[r] = fmaf(p.w, w3, acc[r]);
        }
    }
    #pragma unroll
    for (int r = 0; r < KVROWS; ++r) O[(r0 + r)*DIM + f] = fmaf(sgn, acc[r], addv);
}

// ---------------- spatial binning: count / scan / scatter ----------------
__global__ __launch_bounds__(256) void cellcount_k(
    const float* __restrict__ xyz, int* __restrict__ cnt)
{
    int gid = blockIdx.x*256 + threadIdx.x;
    int b = gid >> 12; int n = gid & (NPTS - 1);
    const float* p = xyz + (b*NPTS + n)*3;
    int cx = cell_of(p[0]);
    int cy = cell_of(p[1]);
    atomicAdd(&cnt[b*NCELL + cy*GRID + cx], 1);
}

__global__ __launch_bounds__(1024) void prefix_k(
    const int* __restrict__ cnt, int* __restrict__ cell_start,
    int* __restrict__ cursor)
{
    __shared__ int s[NCELL];
    int b = blockIdx.x; int t = threadIdx.x;
    int v = cnt[b*NCELL + t];
    s[t] = v;
    __syncthreads();
    for (int off = 1; off < NCELL; off <<= 1) {
        int add = (t >= off) ? s[t - off] : 0;
        __syncthreads();
        s[t] += add;
        __syncthreads();
    }
    int incl = s[t];
    cell_start[b*(NCELL+1) + t] = incl - v;
    cursor[b*NCELL + t] = incl - v;
    if (t == NCELL - 1) cell_start[b*(NCELL+1) + NCELL] = incl;
}

__global__ __launch_bounds__(256) void scatter_k(
    const float* __restrict__ xyz, int* __restrict__ cursor,
    float2* __restrict__ sxy, int* __restrict__ sidx)
{
    int gid = blockIdx.x*256 + threadIdx.x;
    int b = gid >> 12; int n = gid & (NPTS - 1);
    const float* p = xyz + (b*NPTS + n)*3;
    float x = p[0], y = p[1];
    int cx = cell_of(x);
    int cy = cell_of(y);
    int slot = atomicAdd(&cursor[b*NCELL + cy*GRID + cx], 1);
    sxy[b*NPTS + slot] = make_float2(x, y);
    sidx[b*NPTS + slot] = n;
}

// ---------------- exact kNN: grid-binned candidates + 16x wave-argmin ----------------
__global__ __launch_bounds__(256) void knn_k(
    const float* __restrict__ xyz_q, const float2* __restrict__ sxy,
    const int* __restrict__ sidx, const int* __restrict__ cstart,
    int* __restrict__ knn_out)
{
    __shared__ float cand_d[4][CAP];
    __shared__ int   cand_i[4][CAP];
    int t = threadIdx.x; int wid = t >> 6, lane = t & 63;
    int bx = blockIdx.x; int b = bx >> 11; int q = (bx & 2047)*4 + wid;
    float xq = xyz_q[(b*NQ + q)*2 + 0];
    float yq = xyz_q[(b*NQ + q)*2 + 1];
    int cx = cell_of(xq), cy = cell_of(yq);
    const int* cs_b = cstart + b*(NCELL+1);
    float* cd = cand_d[wid]; int* ci = cand_i[wid];
    const float INF = 3.4e38f;
    const float CS = 1.0f/32.0f;
    int* outp = knn_out + (b*NQ + q)*KNN;
    int myIdx = 0;

    for (int R = 2; R < 9; ++R) {
        int x0 = max(cx-R, 0), x1 = min(cx+R, GRID-1);
        int y0 = max(cy-R, 0), y1 = min(cy+R, GRID-1);
        int cnt = 0;
        for (int ry = y0; ry <= y1; ++ry) {
            int s0 = cs_b[ry*GRID + x0];
            int e0 = cs_b[ry*GRID + x1 + 1];
            for (int o = s0 + lane; o < e0; o += 64) {
                float2 p = sxy[b*NPTS + o];
                float dx = __fadd_rn(xq, -p.x);
                float dy = __fadd_rn(yq, -p.y);
                float d = __fadd_rn(__fmul_rn(dx, dx), __fmul_rn(dy, dy));
                int slot = cnt + (o - s0);
                if (slot < CAP) { cd[slot] = d; ci[slot] = o; }
            }
            cnt += e0 - s0;
        }
        asm volatile("s_waitcnt lgkmcnt(0)" ::: "memory");
        __builtin_amdgcn_sched_barrier(0);

        float dr[6];
        #pragma unroll
        for (int k = 0; k < 6; ++k)
            dr[k] = (lane + k*64 < cnt) ? cd[lane + k*64] : INF;
        float d16 = INF;
        for (int r = 0; r < KNN; ++r) {
            float v = dr[0]; int s = lane;
            #pragma unroll
            for (int k = 1; k < 6; ++k)
                if (dr[k] < v) { v = dr[k]; s = lane + k*64; }
            #pragma unroll
            for (int off = 32; off >= 1; off >>= 1) {
                float ov = __shfl_xor(v, off);
                int   os = __shfl_xor(s, off);
                if (ov < v || (ov == v && os < s)) { v = ov; s = os; }
            }
            if (lane == r) myIdx = sidx[b*NPTS + ci[s]];
            if ((s & 63) == lane) {
                int k = s >> 6;
                if      (k == 0) dr[0] = INF;
                else if (k == 1) dr[1] = INF;
                else if (k == 2) dr[2] = INF;
                else if (k == 3) dr[3] = INF;
                else if (k == 4) dr[4] = INF;
                else             dr[5] = INF;
            }
            d16 = v;
        }
        float bl = (x0 > 0)      ? (xq - (float)x0*CS)       : INF;
        float br = (x1 < GRID-1) ? ((float)(x1+1)*CS - xq)   : INF;
        float bb = (y0 > 0)      ? (yq - (float)y0*CS)       : INF;
        float bt = (y1 < GRID-1) ? ((float)(y1+1)*CS - yq)   : INF;
        float safe = fminf(fminf(bl, br), fminf(bb, bt)) - 2e-6f;
        bool whole = (safe > 1e8f);
        bool ok = (cnt >= KNN) && (cnt <= CAP) && (whole || d16 <= safe*safe);
        if (ok || R == 8) {
            if (lane < KNN) outp[lane] = myIdx;
            break;
        }
    }
}

// ---------------- fused MFMA kernel v8: low-register, K=64 pe GEMM, 64 KB LDS ----------------
// 512 threads = 8 waves, 1 query/wave/iter, 4 iters. Register diet: no per-lane
// hoists, c1 pre-folded into K1c, k=32 fixup absorbed into MFMA via eh2.
// Target: total (arch+acc) regs <= 128 -> 4 waves/SIMD (2 blocks/CU by LDS too).
__global__ __launch_bounds__(512, 4) void fuse_k(
    const float* __restrict__ xyz_q, const float* __restrict__ xyz,
    const float* __restrict__ K1c, const float* __restrict__ Vp,
    const int* __restrict__ knn_idx,
    const float* __restrict__ vg_, const float* __restrict__ h2g_,
    const ushort_t* __restrict__ pwf, const ushort_t* __restrict__ w2f,
    float* __restrict__ out)
{
    __shared__ __align__(16) ushort_t w2B[32*512];   // 32 KB
    __shared__ __align__(16) ushort_t h1b[8][2048];  // 32 KB (single bf16, per-wave)

    int t = threadIdx.x, lane = t & 63, wid = t >> 6;
    int bx = blockIdx.x; int b = bx >> 8; int qbase = (bx & 255) * 32;

    {   // stage w2 frags once per block (32 KB)
        const int4* s2 = (const int4*)w2f;  int4* d2 = (int4*)w2B;
        #pragma unroll
        for (int i = 0; i < 4; ++i) d2[t + i*512] = s2[t + i*512];
    }
    __syncthreads();

    int c16 = lane & 15, g = lane >> 4, rowbase = g*4;
    ushort_t* hb = h1b[wid];
    const vshort8* pwBv = (const vshort8*)pwf;       // global, L1/L2-resident
    const vshort8* w2Bv = (const vshort8*)w2B;
    const vfloat4 vzero = (vfloat4){0.f, 0.f, 0.f, 0.f};

    #pragma unroll 1
    for (int qi = 0; qi < 4; ++qi) {
        int q = qbase + wid*4 + qi;
        float xq = xyz_q[(b*NQ + q)*2 + 0];
        float yq = xyz_q[(b*NQ + q)*2 + 1];
        int idxrow = knn_idx[(b*NQ + q)*KNN + c16];
        const float* p = xyz + (b*NPTS + idxrow)*3;
        float pd0 = xq - p[0], pd1 = yq - p[1], pd2 = p[2];
        int idxr[4];
        #pragma unroll
        for (int r = 0; r < 4; ++r) idxr[r] = __shfl(idxrow, rowbase + r);

        // emb A-fragments in registers: eh covers k=0..31 (k = g*8 + j),
        // eh2 covers k=32..63 (only k=32 nonzero: cos(32*z), rows 33..63 of pwc are zero)
        vshort8 eh;
        int k0 = g*8;
        #pragma unroll
        for (int j = 0; j < 8; ++j) {
            int k = k0 + j;
            float v;
            if (k < 3) {
                v = (k == 0) ? pd0 : (k == 1 ? pd1 : pd2);
            } else {
                int m = k - 3; int fi = m / 6; int rem = m - fi*6;
                int comp = (rem < 3) ? rem : rem - 3;
                float pdc = (comp == 0) ? pd0 : (comp == 1 ? pd1 : pd2);
                float fr = (fi == 0) ? 1.0f : (fi == 1) ? 8.75f : (fi == 2) ? 16.5f
                         : (fi == 3) ? 24.25f : 32.0f;
                float arg = pdc * fr;
                v = (rem < 3) ? __sinf(arg) : __cosf(arg);
            }
            eh[j] = (short)bf16_rne(v);
        }
        vshort8 eh2 = (vshort8){0,0,0,0,0,0,0,0};
        if (g == 0) eh2[0] = (short)bf16_rne(__cosf(32.0f * pd2));

        // K1c gather prefetch (transient: dies at end of pe1 phase)
        float k1v[4][8];
        #pragma unroll
        for (int r = 0; r < 4; ++r) {
            const float* kp = K1c + ((b*NPTS + idxr[r]) << 7) + c16;
            #pragma unroll
            for (int n = 0; n < 8; ++n) k1v[r][n] = kp[n*16];
        }

        // pe1 + h1 epilogue, one n at a time (acc live = 4 regs)
        #pragma unroll
        for (int n = 0; n < 8; ++n) {
            vfloat4 a = __builtin_amdgcn_mfma_f32_16x16x32_bf16(
                eh, pwBv[(n*2 + 0)*64 + lane], vzero, 0, 0, 0);
            a = __builtin_amdgcn_mfma_f32_16x16x32_bf16(
                eh2, pwBv[(n*2 + 1)*64 + lane], a, 0, 0, 0);
            int col = n*16 + c16;
            int s = col >> 5;
            int lp = ((col >> 3) & 3) << 4;
            int j = c16 & 7;
            #pragma unroll
            for (int r = 0; r < 4; ++r) {
                float h = fmaxf(k1v[r][n] + a[r], 0.f);
                hb[s*512 + (lp | (rowbase + r))*8 + j] = bf16_rne(h);
            }
        }
        asm volatile("s_waitcnt lgkmcnt(0)" ::: "memory");
        __builtin_amdgcn_sched_barrier(0);

        // GEMM2: [16x128]@[128x128], single bf16
        vfloat4 acc2[8];
        #pragma unroll
        for (int n = 0; n < 8; ++n) acc2[n] = vzero;
        #pragma unroll
        for (int s = 0; s < 4; ++s) {
            vshort8 ah = ((const vshort8*)hb)[s*64 + lane];
            #pragma unroll
            for (int n = 0; n < 8; ++n) {
                vshort8 bh = w2Bv[(n*4 + s)*64 + lane];
                acc2[n] = __builtin_amdgcn_mfma_f32_16x16x32_bf16(ah, bh, acc2[n], 0, 0, 0);
            }
        }

        // softmax over 17 slots; pe2 per-n via 2 MFMA; Vp depth-1 pipelined
        const float* vbase[4];
        #pragma unroll
        for (int r = 0; r < 4; ++r) vbase[r] = Vp + ((b*NPTS + idxr[r]) << 7) + c16;
        float vvp[4];
        #pragma unroll
        for (int r = 0; r < 4; ++r) vvp[r] = vbase[r][0];

        #pragma unroll
        for (int n = 0; n < 8; ++n) {
            float vvc[4];
            #pragma unroll
            for (int r = 0; r < 4; ++r) vvc[r] = vvp[r];
            if (n < 7) {
                #pragma unroll
                for (int r = 0; r < 4; ++r) vvp[r] = vbase[r][(n+1)*16];
            }
            vfloat4 ap = __builtin_amdgcn_mfma_f32_16x16x32_bf16(
                eh, pwBv[((8 + n)*2 + 0)*64 + lane], vzero, 0, 0, 0);
            ap = __builtin_amdgcn_mfma_f32_16x16x32_bf16(
                eh2, pwBv[((8 + n)*2 + 1)*64 + lane], ap, 0, 0, 0);

            float hg = h2g_[b*128 + n*16 + c16];
            vfloat4 a2 = acc2[n];
            float mx = fmaxf(fmaxf(a2[0], a2[1]), fmaxf(a2[2], a2[3]));
            mx = fmaxf(mx, __shfl_xor(mx, 16));
            mx = fmaxf(mx, __shfl_xor(mx, 32));
            mx = fmaxf(mx, hg);
            float sum = 0.f, num = 0.f;
            #pragma unroll
            for (int r = 0; r < 4; ++r) {
                float ev = __expf(a2[r] - mx);
                float v = vvc[r] + ap[r];
                sum += ev;
                num = fmaf(ev, v, num);
            }
            sum += __shfl_xor(sum, 16); sum += __shfl_xor(sum, 32);
            num += __shfl_xor(num, 16); num += __shfl_xor(num, 32);
            float eg = __expf(hg - mx);
            sum += eg;
            num = fmaf(eg, vg_[b*128 + n*16 + c16], num);
            if (g == 0) out[(b*NQ + q)*128 + n*16 + c16] = num / sum;
        }
        asm volatile("s_waitcnt lgkmcnt(0)" ::: "memory");
        __builtin_amdgcn_sched_barrier(0);
    }
}

extern "C" void kernel_launch(void* const* d_in, const int* in_sizes, int n_in,
                              void* d_out, int out_size, void* d_ws, size_t ws_size,
                              hipStream_t stream) {
    const float* xyz_q  = (const float*)d_in[0];
    const float* lat    = (const float*)d_in[1];
    const float* xyz    = (const float*)d_in[2];
    const float* points = (const float*)d_in[3];
    const float* w_qs   = (const float*)d_in[4];
    const float* w_ks   = (const float*)d_in[5];
    const float* w_vs   = (const float*)d_in[6];
    const float* w_kg   = (const float*)d_in[7];
    const float* w_vg   = (const float*)d_in[8];
    const float* g_w1   = (const float*)d_in[9];
    const float* g_b1   = (const float*)d_in[10];
    const float* g_w2   = (const float*)d_in[11];
    const float* g_b2   = (const float*)d_in[12];  // cancels under softmax
    const float* pe_w   = (const float*)d_in[13];
    const float* pe_b   = (const float*)d_in[14];
    float* out = (float*)d_out;
    (void)g_b2;

    float* ws   = (float*)d_ws;
    float* Vp   = ws;                          // 2*4096*128
    float* K1c  = Vp  + NB*NPTS*DIM;           // 2*4096*128
    float* Wk1  = K1c + NB*NPTS*DIM;           // 128*128
    float* pwc  = Wk1 + DIM*DIM;               // 64*256
    float* c1   = pwc + 64*256;                // 256
    float* vg   = c1  + NB*DIM;                // 256
    float* h2g  = vg  + NB*DIM;                // 256
    int*   knn  = (int*)(h2g + NB*DIM);        // 2*8192*16
    ushort_t* pwf = (ushort_t*)(knn + NB*NQ*KNN);   // 16*2*64*8 bf16 = 32 KB
    ushort_t* w2f = pwf + 16*2*64*8;                // 32 KB
    int* cellcnt  = (int*)(w2f + 32*64*8);          // 2*1024
    int* cellstart = cellcnt + NB*NCELL;            // 2*1025
    int* cursor    = cellstart + NB*(NCELL+1);      // 2*1024
    int* sidx      = cursor + NB*NCELL;             // 2*4096
    float2* sxy    = (float2*)(sidx + NB*NPTS);     // 2*4096 float2

    hipMemsetAsync(cellcnt, 0, NB*NCELL*sizeof(int), stream);
    wprod_k<<<192, 128, 0, stream>>>(w_ks, g_w1, pe_w, Wk1, pwc);
    pack_k<<<8, 256, 0, stream>>>(pwc, 64, 256, 16, 2, pwf);
    pack_k<<<8, 256, 0, stream>>>(g_w2, 128, 128, 8, 4, w2f);
    prep_global_k<<<1, 256, 0, stream>>>(lat, w_qs, w_kg, w_vg,
                                         g_w1, g_b1, g_w2, pe_b, c1, vg, h2g);
    cellcount_k<<<NB*NPTS/256, 256, 0, stream>>>(xyz, cellcnt);
    prefix_k<<<NB, 1024, 0, stream>>>(cellcnt, cellstart, cursor);
    scatter_k<<<NB*NPTS/256, 256, 0, stream>>>(xyz, cursor, sxy, sidx);
    kv_proj_k<<<NB*NPTS/KVROWS, 256, 0, stream>>>(points, Wk1, w_vs, pe_b, c1, K1c, Vp);
    knn_k<<<NB*NQ/4, 256, 0, stream>>>(xyz_q, sxy, sidx, cellstart, knn);
    fuse_k<<<NB*NQ/32, 512, 0, stream>>>(xyz_q, xyz, K1c, Vp, knn, vg, h2g,
                                         pwf, w2f, out);
}

// Round 9
// 193.219 us; speedup vs baseline: 1.0129x; 1.0129x over previous
//
#include <hip/hip_runtime.h>
#include <cstdint>

#define DIM   128
#define KNN   16
#define NB    2
#define NQ    8192
#define NPTS  4096
#define KVROWS 16
#define GRID  32
#define NCELL (GRID*GRID)
#define CAP   384

typedef unsigned short ushort_t;
typedef short vshort8 __attribute__((ext_vector_type(8)));
typedef float vfloat4 __attribute__((ext_vector_type(4)));

__device__ __forceinline__ ushort_t bf16_rne(float f) {
    unsigned u = __float_as_uint(f);
    unsigned r = u + 0x7FFFu + ((u >> 16) & 1u);
    return (ushort_t)(r >> 16);
}
__device__ __forceinline__ int cell_of(float x) {
    int c = (int)(x * 32.0f);
    return min(max(c, 0), GRID - 1);
}

// ---------------- W-products: Wk1 = w_ks@g_w1 ; pwc = [pe_w@g_w1 | pe_w] (64x256, rows 33..63 zero) ----------------
__global__ __launch_bounds__(128) void wprod_k(
    const float* __restrict__ w_ks, const float* __restrict__ g_w1,
    const float* __restrict__ pe_w,
    float* __restrict__ Wk1, float* __restrict__ pwc)
{
    int f = threadIdx.x; int blk = blockIdx.x;
    if (blk < 128) {
        float acc = 0.f;
        for (int t = 0; t < 128; ++t) acc = fmaf(w_ks[blk*128 + t], g_w1[t*128 + f], acc);
        Wk1[blk*128 + f] = acc;
    } else {
        int r = blk - 128;                      // 0..63
        for (int h = 0; h < 2; ++h) {
            int col = f + h*128;
            float v = 0.f;
            if (r < 33) {
                if (col < 128) {
                    float a = 0.f;
                    for (int t = 0; t < 128; ++t) a = fmaf(pe_w[r*128 + t], g_w1[t*128 + col], a);
                    v = a;
                } else {
                    v = pe_w[r*128 + (col - 128)];
                }
            }
            pwc[r*256 + col] = v;
        }
    }
}

// ---------------- pack f32 [K][ncols] into MFMA B-fragments, single bf16 ----------------
__global__ __launch_bounds__(256) void pack_k(
    const float* __restrict__ src, int K, int ncols, int NT, int KS,
    ushort_t* __restrict__ dst)
{
    int gid = blockIdx.x*256 + threadIdx.x;
    int total = NT*KS*64;
    if (gid >= total) return;
    int lane = gid & 63; int c = gid >> 6;
    int s = c % KS; int n = c / KS;
    int k0 = s*32 + ((lane >> 4) << 3);
    int col = n*16 + (lane & 15);
    vshort8 v;
    #pragma unroll
    for (int i = 0; i < 8; ++i) {
        int k = k0 + i;
        float f = (k < K) ? src[k*ncols + col] : 0.f;
        v[i] = (short)bf16_rne(f);
    }
    *(vshort8*)(dst + gid*8) = v;
}

// ---------------- per-batch global branch ----------------
__global__ __launch_bounds__(256) void prep_global_k(
    const float* __restrict__ lat, const float* __restrict__ w_qs,
    const float* __restrict__ w_kg, const float* __restrict__ w_vg,
    const float* __restrict__ g_w1, const float* __restrict__ g_b1,
    const float* __restrict__ g_w2, const float* __restrict__ pe_b,
    float* __restrict__ c1_out, float* __restrict__ vg_out, float* __restrict__ h2g_out)
{
    __shared__ float qs[NB][DIM];
    __shared__ float hg[NB][DIM];
    __shared__ float h1g[NB][DIM];
    int t = threadIdx.x; int b = t >> 7; int f = t & 127;
    float aq = 0.f, ak = 0.f, av = 0.f;
    for (int c = 0; c < DIM; ++c) {
        float l = lat[b*DIM + c];
        aq = fmaf(l, w_qs[c*DIM + f], aq);
        ak = fmaf(l, w_kg[c*DIM + f], ak);
        av = fmaf(l, w_vg[c*DIM + f], av);
    }
    vg_out[b*DIM + f] = av;
    qs[b][f] = aq + pe_b[f];
    hg[b][f] = aq - ak;
    __syncthreads();
    float acc = g_b1[f], acch = g_b1[f];
    for (int c = 0; c < DIM; ++c) {
        float w = g_w1[c*DIM + f];
        acc  = fmaf(qs[b][c], w, acc);
        acch = fmaf(hg[b][c], w, acch);
    }
    c1_out[b*DIM + f] = acc;
    h1g[b][f] = fmaxf(acch, 0.f);
    __syncthreads();
    float acc2 = 0.f;                       // b2 dropped (softmax-invariant)
    for (int c = 0; c < DIM; ++c) acc2 = fmaf(h1g[b][c], g_w2[c*DIM + f], acc2);
    h2g_out[b*DIM + f] = acc2;
}

// ---------------- K1c = c1 - points@Wk1 ; Vp' = points@w_vs + pe_b ----------------
__global__ __launch_bounds__(256) void kv_proj_k(
    const float* __restrict__ points, const float* __restrict__ Wk1,
    const float* __restrict__ w_vs, const float* __restrict__ pe_b,
    const float* __restrict__ c1_,
    float* __restrict__ K1c, float* __restrict__ Vp)
{
    __shared__ __align__(16) float pts[KVROWS*DIM];
    int t = threadIdx.x;
    int r0 = blockIdx.x * KVROWS;
    int b = r0 >> 12;
    #pragma unroll
    for (int k = 0; k < KVROWS*DIM/256; ++k) {
        int e = t + k*256;
        pts[e] = points[r0*DIM + e];
    }
    __syncthreads();
    int f = t & 127; int mat = t >> 7;
    const float* W = mat ? w_vs : Wk1;
    float* O = mat ? Vp : K1c;
    float addv = mat ? pe_b[f] : c1_[b*DIM + f];
    float sgn  = mat ? 1.f : -1.f;
    float acc[KVROWS];
    #pragma unroll
    for (int r = 0; r < KVROWS; ++r) acc[r] = 0.f;
    const float4* pts4 = reinterpret_cast<const float4*>(pts);
    for (int c4 = 0; c4 < DIM/4; ++c4) {
        float w0 = W[(c4*4+0)*DIM + f];
        float w1 = W[(c4*4+1)*DIM + f];
        float w2 = W[(c4*4+2)*DIM + f];
        float w3 = W[(c4*4+3)*DIM + f];
        #pragma unroll
        for (int r = 0; r < KVROWS; ++r) {
            float4 p = pts4[r*(DIM/4) + c4];
            acc[r] = fmaf(p.x, w0, acc[r]);
            acc[r] = fmaf(p.y, w1, acc[r]);
            acc[r] = fmaf(p.z, w2, acc[r]);
            acc[r] = fmaf(p.w, w3, acc[r]);
        }
    }
    #pragma unroll
    for (int r = 0; r < KVROWS; ++r) O[(r0 + r)*DIM + f] = fmaf(sgn, acc[r], addv);
}

// ---------------- spatial binning: count / scan / scatter ----------------
__global__ __launch_bounds__(256) void cellcount_k(
    const float* __restrict__ xyz, int* __restrict__ cnt)
{
    int gid = blockIdx.x*256 + threadIdx.x;
    int b = gid >> 12; int n = gid & (NPTS - 1);
    const float* p = xyz + (b*NPTS + n)*3;
    int cx = cell_of(p[0]);
    int cy = cell_of(p[1]);
    atomicAdd(&cnt[b*NCELL + cy*GRID + cx], 1);
}

__global__ __launch_bounds__(1024) void prefix_k(
    const int* __restrict__ cnt, int* __restrict__ cell_start,
    int* __restrict__ cursor)
{
    __shared__ int s[NCELL];
    int b = blockIdx.x; int t = threadIdx.x;
    int v = cnt[b*NCELL + t];
    s[t] = v;
    __syncthreads();
    for (int off = 1; off < NCELL; off <<= 1) {
        int add = (t >= off) ? s[t - off] : 0;
        __syncthreads();
        s[t] += add;
        __syncthreads();
    }
    int incl = s[t];
    cell_start[b*(NCELL+1) + t] = incl - v;
    cursor[b*NCELL + t] = incl - v;
    if (t == NCELL - 1) cell_start[b*(NCELL+1) + NCELL] = incl;
}

__global__ __launch_bounds__(256) void scatter_k(
    const float* __restrict__ xyz, int* __restrict__ cursor,
    float2* __restrict__ sxy, int* __restrict__ sidx)
{
    int gid = blockIdx.x*256 + threadIdx.x;
    int b = gid >> 12; int n = gid & (NPTS - 1);
    const float* p = xyz + (b*NPTS + n)*3;
    float x = p[0], y = p[1];
    int cx = cell_of(x);
    int cy = cell_of(y);
    int slot = atomicAdd(&cursor[b*NCELL + cy*GRID + cx], 1);
    sxy[b*NPTS + slot] = make_float2(x, y);
    sidx[b*NPTS + slot] = n;
}

// ---------------- exact kNN: grid-binned candidates + 16x wave-argmin ----------------
__global__ __launch_bounds__(256) void knn_k(
    const float* __restrict__ xyz_q, const float2* __restrict__ sxy,
    const int* __restrict__ sidx, const int* __restrict__ cstart,
    int* __restrict__ knn_out)
{
    __shared__ float cand_d[4][CAP];
    __shared__ int   cand_i[4][CAP];
    int t = threadIdx.x; int wid = t >> 6, lane = t & 63;
    int bx = blockIdx.x; int b = bx >> 11; int q = (bx & 2047)*4 + wid;
    float xq = xyz_q[(b*NQ + q)*2 + 0];
    float yq = xyz_q[(b*NQ + q)*2 + 1];
    int cx = cell_of(xq), cy = cell_of(yq);
    const int* cs_b = cstart + b*(NCELL+1);
    float* cd = cand_d[wid]; int* ci = cand_i[wid];
    const float INF = 3.4e38f;
    const float CS = 1.0f/32.0f;
    int* outp = knn_out + (b*NQ + q)*KNN;
    int myIdx = 0;

    for (int R = 2; R < 9; ++R) {
        int x0 = max(cx-R, 0), x1 = min(cx+R, GRID-1);
        int y0 = max(cy-R, 0), y1 = min(cy+R, GRID-1);
        int cnt = 0;
        for (int ry = y0; ry <= y1; ++ry) {
            int s0 = cs_b[ry*GRID + x0];
            int e0 = cs_b[ry*GRID + x1 + 1];
            for (int o = s0 + lane; o < e0; o += 64) {
                float2 p = sxy[b*NPTS + o];
                float dx = __fadd_rn(xq, -p.x);
                float dy = __fadd_rn(yq, -p.y);
                float d = __fadd_rn(__fmul_rn(dx, dx), __fmul_rn(dy, dy));
                int slot = cnt + (o - s0);
                if (slot < CAP) { cd[slot] = d; ci[slot] = o; }
            }
            cnt += e0 - s0;
        }
        asm volatile("s_waitcnt lgkmcnt(0)" ::: "memory");
        __builtin_amdgcn_sched_barrier(0);

        float dr[6];
        #pragma unroll
        for (int k = 0; k < 6; ++k)
            dr[k] = (lane + k*64 < cnt) ? cd[lane + k*64] : INF;
        float d16 = INF;
        for (int r = 0; r < KNN; ++r) {
            float v = dr[0]; int s = lane;
            #pragma unroll
            for (int k = 1; k < 6; ++k)
                if (dr[k] < v) { v = dr[k]; s = lane + k*64; }
            #pragma unroll
            for (int off = 32; off >= 1; off >>= 1) {
                float ov = __shfl_xor(v, off);
                int   os = __shfl_xor(s, off);
                if (ov < v || (ov == v && os < s)) { v = ov; s = os; }
            }
            if (lane == r) myIdx = sidx[b*NPTS + ci[s]];
            if ((s & 63) == lane) {
                int k = s >> 6;
                if      (k == 0) dr[0] = INF;
                else if (k == 1) dr[1] = INF;
                else if (k == 2) dr[2] = INF;
                else if (k == 3) dr[3] = INF;
                else if (k == 4) dr[4] = INF;
                else             dr[5] = INF;
            }
            d16 = v;
        }
        float bl = (x0 > 0)      ? (xq - (float)x0*CS)       : INF;
        float br = (x1 < GRID-1) ? ((float)(x1+1)*CS - xq)   : INF;
        float bb = (y0 > 0)      ? (yq - (float)y0*CS)       : INF;
        float bt = (y1 < GRID-1) ? ((float)(y1+1)*CS - yq)   : INF;
        float safe = fminf(fminf(bl, br), fminf(bb, bt)) - 2e-6f;
        bool whole = (safe > 1e8f);
        bool ok = (cnt >= KNN) && (cnt <= CAP) && (whole || d16 <= safe*safe);
        if (ok || R == 8) {
            if (lane < KNN) outp[lane] = myIdx;
            break;
        }
    }
}

// ---------------- fused MFMA kernel v9: register-diet + n-merged GEMM2/softmax ----------------
// 512 threads = 8 waves, 1 query/wave/iter, 4 iters. Live-set engineered <=128 total
// (incl unified AGPR acc): acc2[8]->per-n acc (4), k1v 32->2x16 batches, ah cached (16).
// 64 KB LDS -> 2 blocks/CU; target 4 waves/SIMD.
__global__ __launch_bounds__(512, 4) void fuse_k(
    const float* __restrict__ xyz_q, const float* __restrict__ xyz,
    const float* __restrict__ K1c, const float* __restrict__ Vp,
    const int* __restrict__ knn_idx,
    const float* __restrict__ vg_, const float* __restrict__ h2g_,
    const ushort_t* __restrict__ pwf, const ushort_t* __restrict__ w2f,
    float* __restrict__ out)
{
    __shared__ __align__(16) ushort_t w2B[32*512];   // 32 KB
    __shared__ __align__(16) ushort_t h1b[8][2048];  // 32 KB (single bf16, per-wave)

    int t = threadIdx.x, lane = t & 63, wid = t >> 6;
    int bx = blockIdx.x; int b = bx >> 8; int qbase = (bx & 255) * 32;

    {   // stage w2 frags once per block (32 KB)
        const int4* s2 = (const int4*)w2f;  int4* d2 = (int4*)w2B;
        #pragma unroll
        for (int i = 0; i < 4; ++i) d2[t + i*512] = s2[t + i*512];
    }
    __syncthreads();

    int c16 = lane & 15, g = lane >> 4, rowbase = g*4;
    ushort_t* hb = h1b[wid];
    const vshort8* pwBv = (const vshort8*)pwf;       // global, L1/L2-resident
    const vshort8* w2Bv = (const vshort8*)w2B;
    const vfloat4 vzero = (vfloat4){0.f, 0.f, 0.f, 0.f};

    #pragma unroll 1
    for (int qi = 0; qi < 4; ++qi) {
        int q = qbase + wid*4 + qi;
        float xq = xyz_q[(b*NQ + q)*2 + 0];
        float yq = xyz_q[(b*NQ + q)*2 + 1];
        int idxrow = knn_idx[(b*NQ + q)*KNN + c16];
        const float* p = xyz + (b*NPTS + idxrow)*3;
        float pd0 = xq - p[0], pd1 = yq - p[1], pd2 = p[2];
        int goff[4];   // element offsets into K1c/Vp for this lane's 4 C-rows
        #pragma unroll
        for (int r = 0; r < 4; ++r)
            goff[r] = (((b*NPTS + __shfl(idxrow, rowbase + r)) << 7) + c16);

        // emb A-fragments: eh covers k=0..31 (k = g*8 + j), eh2 covers k=32 (cos(32 z))
        vshort8 eh;
        int k0 = g*8;
        #pragma unroll
        for (int j = 0; j < 8; ++j) {
            int k = k0 + j;
            float v;
            if (k < 3) {
                v = (k == 0) ? pd0 : (k == 1 ? pd1 : pd2);
            } else {
                int m = k - 3; int fi = m / 6; int rem = m - fi*6;
                int comp = (rem < 3) ? rem : rem - 3;
                float pdc = (comp == 0) ? pd0 : (comp == 1 ? pd1 : pd2);
                float fr = (fi == 0) ? 1.0f : (fi == 1) ? 8.75f : (fi == 2) ? 16.5f
                         : (fi == 3) ? 24.25f : 32.0f;
                float arg = pdc * fr;
                v = (rem < 3) ? __sinf(arg) : __cosf(arg);
            }
            eh[j] = (short)bf16_rne(v);
        }
        vshort8 eh2 = (vshort8){0,0,0,0,0,0,0,0};
        if (g == 0) eh2[0] = (short)bf16_rne(__cosf(32.0f * pd2));

        // pe1 + h1 epilogue in two half-batches (k1v live = 16 regs)
        #pragma unroll
        for (int half = 0; half < 2; ++half) {
            float k1v[4][4];   // [nn][r]
            #pragma unroll
            for (int r = 0; r < 4; ++r) {
                #pragma unroll
                for (int nn = 0; nn < 4; ++nn)
                    k1v[nn][r] = K1c[goff[r] + (half*4 + nn)*16];
            }
            #pragma unroll
            for (int nn = 0; nn < 4; ++nn) {
                int n = half*4 + nn;
                vfloat4 a = __builtin_amdgcn_mfma_f32_16x16x32_bf16(
                    eh, pwBv[(n*2 + 0)*64 + lane], vzero, 0, 0, 0);
                a = __builtin_amdgcn_mfma_f32_16x16x32_bf16(
                    eh2, pwBv[(n*2 + 1)*64 + lane], a, 0, 0, 0);
                int col = n*16 + c16;
                int s = col >> 5;
                int lp = ((col >> 3) & 3) << 4;
                int j = c16 & 7;
                #pragma unroll
                for (int r = 0; r < 4; ++r) {
                    float h = fmaxf(k1v[nn][r] + a[r], 0.f);
                    hb[s*512 + (lp | (rowbase + r))*8 + j] = bf16_rne(h);
                }
            }
        }
        asm volatile("s_waitcnt lgkmcnt(0)" ::: "memory");
        __builtin_amdgcn_sched_barrier(0);

        // h1 A-fragments once (16 regs; k1v is dead here)
        vshort8 ah[4];
        #pragma unroll
        for (int s = 0; s < 4; ++s) ah[s] = ((const vshort8*)hb)[s*64 + lane];

        // merged GEMM2 + pe2 + softmax, per 16-feature group n (acc live = 4 regs)
        float vvp[4];
        #pragma unroll
        for (int r = 0; r < 4; ++r) vvp[r] = Vp[goff[r]];

        #pragma unroll
        for (int n = 0; n < 8; ++n) {
            float vvc[4];
            #pragma unroll
            for (int r = 0; r < 4; ++r) vvc[r] = vvp[r];
            if (n < 7) {
                #pragma unroll
                for (int r = 0; r < 4; ++r) vvp[r] = Vp[goff[r] + (n+1)*16];
            }
            vfloat4 ap = __builtin_amdgcn_mfma_f32_16x16x32_bf16(
                eh, pwBv[((8 + n)*2 + 0)*64 + lane], vzero, 0, 0, 0);
            ap = __builtin_amdgcn_mfma_f32_16x16x32_bf16(
                eh2, pwBv[((8 + n)*2 + 1)*64 + lane], ap, 0, 0, 0);
            vfloat4 a2 = vzero;
            #pragma unroll
            for (int s = 0; s < 4; ++s)
                a2 = __builtin_amdgcn_mfma_f32_16x16x32_bf16(
                    ah[s], w2Bv[(n*4 + s)*64 + lane], a2, 0, 0, 0);

            float hg = h2g_[b*128 + n*16 + c16];
            float mx = fmaxf(fmaxf(a2[0], a2[1]), fmaxf(a2[2], a2[3]));
            mx = fmaxf(mx, __shfl_xor(mx, 16));
            mx = fmaxf(mx, __shfl_xor(mx, 32));
            mx = fmaxf(mx, hg);
            float sum = 0.f, num = 0.f;
            #pragma unroll
            for (int r = 0; r < 4; ++r) {
                float ev = __expf(a2[r] - mx);
                float v = vvc[r] + ap[r];
                sum += ev;
                num = fmaf(ev, v, num);
            }
            sum += __shfl_xor(sum, 16); sum += __shfl_xor(sum, 32);
            num += __shfl_xor(num, 16); num += __shfl_xor(num, 32);
            float eg = __expf(hg - mx);
            sum += eg;
            num = fmaf(eg, vg_[b*128 + n*16 + c16], num);
            if (g == 0) out[(b*NQ + q)*128 + n*16 + c16] = num / sum;
        }
        asm volatile("s_waitcnt lgkmcnt(0)" ::: "memory");
        __builtin_amdgcn_sched_barrier(0);
    }
}

extern "C" void kernel_launch(void* const* d_in, const int* in_sizes, int n_in,
                              void* d_out, int out_size, void* d_ws, size_t ws_size,
                              hipStream_t stream) {
    const float* xyz_q  = (const float*)d_in[0];
    const float* lat    = (const float*)d_in[1];
    const float* xyz    = (const float*)d_in[2];
    const float* points = (const float*)d_in[3];
    const float* w_qs   = (const float*)d_in[4];
    const float* w_ks   = (const float*)d_in[5];
    const float* w_vs   = (const float*)d_in[6];
    const float* w_kg   = (const float*)d_in[7];
    const float* w_vg   = (const float*)d_in[8];
    const float* g_w1   = (const float*)d_in[9];
    const float* g_b1   = (const float*)d_in[10];
    const float* g_w2   = (const float*)d_in[11];
    const float* g_b2   = (const float*)d_in[12];  // cancels under softmax
    const float* pe_w   = (const float*)d_in[13];
    const float* pe_b   = (const float*)d_in[14];
    float* out = (float*)d_out;
    (void)g_b2;

    float* ws   = (float*)d_ws;
    float* Vp   = ws;                          // 2*4096*128
    float* K1c  = Vp  + NB*NPTS*DIM;           // 2*4096*128
    float* Wk1  = K1c + NB*NPTS*DIM;           // 128*128
    float* pwc  = Wk1 + DIM*DIM;               // 64*256
    float* c1   = pwc + 64*256;                // 256
    float* vg   = c1  + NB*DIM;                // 256
    float* h2g  = vg  + NB*DIM;                // 256
    int*   knn  = (int*)(h2g + NB*DIM);        // 2*8192*16
    ushort_t* pwf = (ushort_t*)(knn + NB*NQ*KNN);   // 16*2*64*8 bf16 = 32 KB
    ushort_t* w2f = pwf + 16*2*64*8;                // 32 KB
    int* cellcnt  = (int*)(w2f + 32*64*8);          // 2*1024
    int* cellstart = cellcnt + NB*NCELL;            // 2*1025
    int* cursor    = cellstart + NB*(NCELL+1);      // 2*1024
    int* sidx      = cursor + NB*NCELL;             // 2*4096
    float2* sxy    = (float2*)(sidx + NB*NPTS);     // 2*4096 float2

    hipMemsetAsync(cellcnt, 0, NB*NCELL*sizeof(int), stream);
    wprod_k<<<192, 128, 0, stream>>>(w_ks, g_w1, pe_w, Wk1, pwc);
    pack_k<<<8, 256, 0, stream>>>(pwc, 64, 256, 16, 2, pwf);
    pack_k<<<8, 256, 0, stream>>>(g_w2, 128, 128, 8, 4, w2f);
    prep_global_k<<<1, 256, 0, stream>>>(lat, w_qs, w_kg, w_vg,
                                         g_w1, g_b1, g_w2, pe_b, c1, vg, h2g);
    cellcount_k<<<NB*NPTS/256, 256, 0, stream>>>(xyz, cellcnt);
    prefix_k<<<NB, 1024, 0, stream>>>(cellcnt, cellstart, cursor);
    scatter_k<<<NB*NPTS/256, 256, 0, stream>>>(xyz, cursor, sxy, sidx);
    kv_proj_k<<<NB*NPTS/KVROWS, 256, 0, stream>>>(points, Wk1, w_vs, pe_b, c1, K1c, Vp);
    knn_k<<<NB*NQ/4, 256, 0, stream>>>(xyz_q, sxy, sidx, cellstart, knn);
    fuse_k<<<NB*NQ/32, 512, 0, stream>>>(xyz_q, xyz, K1c, Vp, knn, vg, h2g,
                                         pwf, w2f, out);
}

// Round 10
// 185.193 us; speedup vs baseline: 1.0568x; 1.0433x over previous
//
#include <hip/hip_runtime.h>
#include <cstdint>

#define DIM   128
#define KNN   16
#define NB    2
#define NQ    8192
#define NPTS  4096
#define KVROWS 16
#define GRID  32
#define NCELL (GRID*GRID)
#define CAP   384

typedef unsigned short ushort_t;
typedef short vshort8 __attribute__((ext_vector_type(8)));
typedef float vfloat4 __attribute__((ext_vector_type(4)));

__device__ __forceinline__ ushort_t bf16_rne(float f) {
    unsigned u = __float_as_uint(f);
    unsigned r = u + 0x7FFFu + ((u >> 16) & 1u);
    return (ushort_t)(r >> 16);
}
__device__ __forceinline__ int cell_of(float x) {
    int c = (int)(x * 32.0f);
    return min(max(c, 0), GRID - 1);
}

// ---------------- W-products: Wk1 = w_ks@g_w1 ; pwc = [pe_w@g_w1 | pe_w] (64x256, rows 33..63 zero) ----------------
__global__ __launch_bounds__(128) void wprod_k(
    const float* __restrict__ w_ks, const float* __restrict__ g_w1,
    const float* __restrict__ pe_w,
    float* __restrict__ Wk1, float* __restrict__ pwc)
{
    int f = threadIdx.x; int blk = blockIdx.x;
    if (blk < 128) {
        float acc = 0.f;
        for (int t = 0; t < 128; ++t) acc = fmaf(w_ks[blk*128 + t], g_w1[t*128 + f], acc);
        Wk1[blk*128 + f] = acc;
    } else {
        int r = blk - 128;                      // 0..63
        for (int h = 0; h < 2; ++h) {
            int col = f + h*128;
            float v = 0.f;
            if (r < 33) {
                if (col < 128) {
                    float a = 0.f;
                    for (int t = 0; t < 128; ++t) a = fmaf(pe_w[r*128 + t], g_w1[t*128 + col], a);
                    v = a;
                } else {
                    v = pe_w[r*128 + (col - 128)];
                }
            }
            pwc[r*256 + col] = v;
        }
    }
}

// ---------------- pack f32 [K][ncols] into MFMA B-fragments, single bf16 ----------------
__global__ __launch_bounds__(256) void pack_k(
    const float* __restrict__ src, int K, int ncols, int NT, int KS,
    ushort_t* __restrict__ dst)
{
    int gid = blockIdx.x*256 + threadIdx.x;
    int total = NT*KS*64;
    if (gid >= total) return;
    int lane = gid & 63; int c = gid >> 6;
    int s = c % KS; int n = c / KS;
    int k0 = s*32 + ((lane >> 4) << 3);
    int col = n*16 + (lane & 15);
    vshort8 v;
    #pragma unroll
    for (int i = 0; i < 8; ++i) {
        int k = k0 + i;
        float f = (k < K) ? src[k*ncols + col] : 0.f;
        v[i] = (short)bf16_rne(f);
    }
    *(vshort8*)(dst + gid*8) = v;
}

// ---------------- per-batch global branch ----------------
__global__ __launch_bounds__(256) void prep_global_k(
    const float* __restrict__ lat, const float* __restrict__ w_qs,
    const float* __restrict__ w_kg, const float* __restrict__ w_vg,
    const float* __restrict__ g_w1, const float* __restrict__ g_b1,
    const float* __restrict__ g_w2, const float* __restrict__ pe_b,
    float* __restrict__ c1_out, float* __restrict__ vg_out, float* __restrict__ h2g_out)
{
    __shared__ float qs[NB][DIM];
    __shared__ float hg[NB][DIM];
    __shared__ float h1g[NB][DIM];
    int t = threadIdx.x; int b = t >> 7; int f = t & 127;
    float aq = 0.f, ak = 0.f, av = 0.f;
    for (int c = 0; c < DIM; ++c) {
        float l = lat[b*DIM + c];
        aq = fmaf(l, w_qs[c*DIM + f], aq);
        ak = fmaf(l, w_kg[c*DIM + f], ak);
        av = fmaf(l, w_vg[c*DIM + f], av);
    }
    vg_out[b*DIM + f] = av;
    qs[b][f] = aq + pe_b[f];
    hg[b][f] = aq - ak;
    __syncthreads();
    float acc = g_b1[f], acch = g_b1[f];
    for (int c = 0; c < DIM; ++c) {
        float w = g_w1[c*DIM + f];
        acc  = fmaf(qs[b][c], w, acc);
        acch = fmaf(hg[b][c], w, acch);
    }
    c1_out[b*DIM + f] = acc;
    h1g[b][f] = fmaxf(acch, 0.f);
    __syncthreads();
    float acc2 = 0.f;                       // b2 dropped (softmax-invariant)
    for (int c = 0; c < DIM; ++c) acc2 = fmaf(h1g[b][c], g_w2[c*DIM + f], acc2);
    h2g_out[b*DIM + f] = acc2;
}

// ---------------- K1c = c1 - points@Wk1 ; Vp' = points@w_vs + pe_b ----------------
// OUTPUT IN FRAGMENT-MAJOR ROW LAYOUT: element (row, col) stored at
// row*128 + (col&15)*8 + (col>>4)  -> lane (g,c16) in fuse_k reads its 8
// needed values (cols c16+n*16, n=0..7) as two contiguous float4s.
__global__ __launch_bounds__(256) void kv_proj_k(
    const float* __restrict__ points, const float* __restrict__ Wk1,
    const float* __restrict__ w_vs, const float* __restrict__ pe_b,
    const float* __restrict__ c1_,
    float* __restrict__ K1c, float* __restrict__ Vp)
{
    __shared__ __align__(16) float pts[KVROWS*DIM];
    int t = threadIdx.x;
    int r0 = blockIdx.x * KVROWS;
    int b = r0 >> 12;
    #pragma unroll
    for (int k = 0; k < KVROWS*DIM/256; ++k) {
        int e = t + k*256;
        pts[e] = points[r0*DIM + e];
    }
    __syncthreads();
    int f = t & 127; int mat = t >> 7;
    const float* W = mat ? w_vs : Wk1;
    float* O = mat ? Vp : K1c;
    float addv = mat ? pe_b[f] : c1_[b*DIM + f];
    float sgn  = mat ? 1.f : -1.f;
    int fc = (f & 15)*8 + (f >> 4);         // fragment-major position within row
    float acc[KVROWS];
    #pragma unroll
    for (int r = 0; r < KVROWS; ++r) acc[r] = 0.f;
    const float4* pts4 = reinterpret_cast<const float4*>(pts);
    for (int c4 = 0; c4 < DIM/4; ++c4) {
        float w0 = W[(c4*4+0)*DIM + f];
        float w1 = W[(c4*4+1)*DIM + f];
        float w2 = W[(c4*4+2)*DIM + f];
        float w3 = W[(c4*4+3)*DIM + f];
        #pragma unroll
        for (int r = 0; r < KVROWS; ++r) {
            float4 p = pts4[r*(DIM/4) + c4];
            acc[r] = fmaf(p.x, w0, acc[r]);
            acc[r] = fmaf(p.y, w1, acc[r]);
            acc[r] = fmaf(p.z, w2, acc[r]);
            acc[r] = fmaf(p.w, w3, acc[r]);
        }
    }
    #pragma unroll
    for (int r = 0; r < KVROWS; ++r) O[(r0 + r)*DIM + fc] = fmaf(sgn, acc[r], addv);
}

// ---------------- spatial binning: count / scan / scatter ----------------
__global__ __launch_bounds__(256) void cellcount_k(
    const float* __restrict__ xyz, int* __restrict__ cnt)
{
    int gid = blockIdx.x*256 + threadIdx.x;
    int b = gid >> 12; int n = gid & (NPTS - 1);
    const float* p = xyz + (b*NPTS + n)*3;
    int cx = cell_of(p[0]);
    int cy = cell_of(p[1]);
    atomicAdd(&cnt[b*NCELL + cy*GRID + cx], 1);
}

__global__ __launch_bounds__(1024) void prefix_k(
    const int* __restrict__ cnt, int* __restrict__ cell_start,
    int* __restrict__ cursor)
{
    __shared__ int s[NCELL];
    int b = blockIdx.x; int t = threadIdx.x;
    int v = cnt[b*NCELL + t];
    s[t] = v;
    __syncthreads();
    for (int off = 1; off < NCELL; off <<= 1) {
        int add = (t >= off) ? s[t - off] : 0;
        __syncthreads();
        s[t] += add;
        __syncthreads();
    }
    int incl = s[t];
    cell_start[b*(NCELL+1) + t] = incl - v;
    cursor[b*NCELL + t] = incl - v;
    if (t == NCELL - 1) cell_start[b*(NCELL+1) + NCELL] = incl;
}

__global__ __launch_bounds__(256) void scatter_k(
    const float* __restrict__ xyz, int* __restrict__ cursor,
    float2* __restrict__ sxy, int* __restrict__ sidx)
{
    int gid = blockIdx.x*256 + threadIdx.x;
    int b = gid >> 12; int n = gid & (NPTS - 1);
    const float* p = xyz + (b*NPTS + n)*3;
    float x = p[0], y = p[1];
    int cx = cell_of(x);
    int cy = cell_of(y);
    int slot = atomicAdd(&cursor[b*NCELL + cy*GRID + cx], 1);
    sxy[b*NPTS + slot] = make_float2(x, y);
    sidx[b*NPTS + slot] = n;
}

// ---------------- exact kNN: grid-binned candidates + 16x wave-argmin ----------------
__global__ __launch_bounds__(256) void knn_k(
    const float* __restrict__ xyz_q, const float2* __restrict__ sxy,
    const int* __restrict__ sidx, const int* __restrict__ cstart,
    int* __restrict__ knn_out)
{
    __shared__ float cand_d[4][CAP];
    __shared__ int   cand_i[4][CAP];
    int t = threadIdx.x; int wid = t >> 6, lane = t & 63;
    int bx = blockIdx.x; int b = bx >> 11; int q = (bx & 2047)*4 + wid;
    float xq = xyz_q[(b*NQ + q)*2 + 0];
    float yq = xyz_q[(b*NQ + q)*2 + 1];
    int cx = cell_of(xq), cy = cell_of(yq);
    const int* cs_b = cstart + b*(NCELL+1);
    float* cd = cand_d[wid]; int* ci = cand_i[wid];
    const float INF = 3.4e38f;
    const float CS = 1.0f/32.0f;
    int* outp = knn_out + (b*NQ + q)*KNN;
    int myIdx = 0;

    for (int R = 2; R < 9; ++R) {
        int x0 = max(cx-R, 0), x1 = min(cx+R, GRID-1);
        int y0 = max(cy-R, 0), y1 = min(cy+R, GRID-1);
        int cnt = 0;
        for (int ry = y0; ry <= y1; ++ry) {
            int s0 = cs_b[ry*GRID + x0];
            int e0 = cs_b[ry*GRID + x1 + 1];
            for (int o = s0 + lane; o < e0; o += 64) {
                float2 p = sxy[b*NPTS + o];
                float dx = __fadd_rn(xq, -p.x);
                float dy = __fadd_rn(yq, -p.y);
                float d = __fadd_rn(__fmul_rn(dx, dx), __fmul_rn(dy, dy));
                int slot = cnt + (o - s0);
                if (slot < CAP) { cd[slot] = d; ci[slot] = o; }
            }
            cnt += e0 - s0;
        }
        asm volatile("s_waitcnt lgkmcnt(0)" ::: "memory");
        __builtin_amdgcn_sched_barrier(0);

        float dr[6];
        #pragma unroll
        for (int k = 0; k < 6; ++k)
            dr[k] = (lane + k*64 < cnt) ? cd[lane + k*64] : INF;
        float d16 = INF;
        for (int r = 0; r < KNN; ++r) {
            float v = dr[0]; int s = lane;
            #pragma unroll
            for (int k = 1; k < 6; ++k)
                if (dr[k] < v) { v = dr[k]; s = lane + k*64; }
            #pragma unroll
            for (int off = 32; off >= 1; off >>= 1) {
                float ov = __shfl_xor(v, off);
                int   os = __shfl_xor(s, off);
                if (ov < v || (ov == v && os < s)) { v = ov; s = os; }
            }
            if (lane == r) myIdx = sidx[b*NPTS + ci[s]];
            if ((s & 63) == lane) {
                int k = s >> 6;
                if      (k == 0) dr[0] = INF;
                else if (k == 1) dr[1] = INF;
                else if (k == 2) dr[2] = INF;
                else if (k == 3) dr[3] = INF;
                else if (k == 4) dr[4] = INF;
                else             dr[5] = INF;
            }
            d16 = v;
        }
        float bl = (x0 > 0)      ? (xq - (float)x0*CS)       : INF;
        float br = (x1 < GRID-1) ? ((float)(x1+1)*CS - xq)   : INF;
        float bb = (y0 > 0)      ? (yq - (float)y0*CS)       : INF;
        float bt = (y1 < GRID-1) ? ((float)(y1+1)*CS - yq)   : INF;
        float safe = fminf(fminf(bl, br), fminf(bb, bt)) - 2e-6f;
        bool whole = (safe > 1e8f);
        bool ok = (cnt >= KNN) && (cnt <= CAP) && (whole || d16 <= safe*safe);
        if (ok || R == 8) {
            if (lane < KNN) outp[lane] = myIdx;
            break;
        }
    }
}

// ---------------- fused MFMA kernel v10: 256-thr blocks (granular occupancy) + float4 gathers ----------------
// 4 waves/block, 1 query/wave/iter, 4 iters (16 q/block). ~49 KB LDS -> 3 blocks/CU
// by LDS; launch_bounds(256,3) sets a ~170-reg budget the natural ~156-reg live set
// fits WITHOUT spilling -> 12 waves/CU (3/SIMD). K1c/Vp fragment-major: per-lane
// needed values contiguous -> dwordx4 gathers (64 scalar loads -> 16 vector loads).
__global__ __launch_bounds__(256, 3) void fuse_k(
    const float* __restrict__ xyz_q, const float* __restrict__ xyz,
    const float* __restrict__ K1c, const float* __restrict__ Vp,
    const int* __restrict__ knn_idx,
    const float* __restrict__ vg_, const float* __restrict__ h2g_,
    const ushort_t* __restrict__ pwf, const ushort_t* __restrict__ w2f,
    float* __restrict__ out)
{
    __shared__ __align__(16) ushort_t w2B[32*512];   // 32 KB
    __shared__ __align__(16) ushort_t h1b[4][2048];  // 16 KB (single bf16, per-wave)
    __shared__ float hgs[128], vgs[128];             // 1 KB

    int t = threadIdx.x, lane = t & 63, wid = t >> 6;
    int bx = blockIdx.x; int b = bx >> 9; int qbase = (bx & 511) * 16;

    {   // stage w2 frags (32 KB) + per-batch vectors once per block
        const int4* s2 = (const int4*)w2f;  int4* d2 = (int4*)w2B;
        #pragma unroll
        for (int i = 0; i < 8; ++i) d2[t + i*256] = s2[t + i*256];
        if (t < 128) {
            hgs[t] = h2g_[b*128 + t];
            vgs[t] = vg_[b*128 + t];
        }
    }
    __syncthreads();

    int c16 = lane & 15, g = lane >> 4, rowbase = g*4;
    ushort_t* hb = h1b[wid];
    const vshort8* pwBv = (const vshort8*)pwf;       // global, L1/L2-resident
    const vshort8* w2Bv = (const vshort8*)w2B;
    const float4* K4 = (const float4*)K1c;
    const float4* V4 = (const float4*)Vp;
    const vfloat4 vzero = (vfloat4){0.f, 0.f, 0.f, 0.f};

    #pragma unroll 1
    for (int qi = 0; qi < 4; ++qi) {
        int q = qbase + wid*4 + qi;
        float xq = xyz_q[(b*NQ + q)*2 + 0];
        float yq = xyz_q[(b*NQ + q)*2 + 1];
        int idxrow = knn_idx[(b*NQ + q)*KNN + c16];
        const float* p = xyz + (b*NPTS + idxrow)*3;
        float pd0 = xq - p[0], pd1 = yq - p[1], pd2 = p[2];
        int rf4[4];   // float4 base index of this lane's span in rows rowbase..rowbase+3
        #pragma unroll
        for (int r = 0; r < 4; ++r)
            rf4[r] = (b*NPTS + __shfl(idxrow, rowbase + r))*32 + c16*2;

        // emb A-fragments: eh covers k=0..31 (k = g*8 + j), eh2 covers k=32 (cos(32 z))
        vshort8 eh;
        int k0 = g*8;
        #pragma unroll
        for (int j = 0; j < 8; ++j) {
            int k = k0 + j;
            float v;
            if (k < 3) {
                v = (k == 0) ? pd0 : (k == 1 ? pd1 : pd2);
            } else {
                int m = k - 3; int fi = m / 6; int rem = m - fi*6;
                int comp = (rem < 3) ? rem : rem - 3;
                float pdc = (comp == 0) ? pd0 : (comp == 1 ? pd1 : pd2);
                float fr = (fi == 0) ? 1.0f : (fi == 1) ? 8.75f : (fi == 2) ? 16.5f
                         : (fi == 3) ? 24.25f : 32.0f;
                float arg = pdc * fr;
                v = (rem < 3) ? __sinf(arg) : __cosf(arg);
            }
            eh[j] = (short)bf16_rne(v);
        }
        vshort8 eh2 = (vshort8){0,0,0,0,0,0,0,0};
        if (g == 0) eh2[0] = (short)bf16_rne(__cosf(32.0f * pd2));

        // pe1 + h1 epilogue in two half-batches; K1c gathers are float4
        #pragma unroll
        for (int half = 0; half < 2; ++half) {
            float4 k1q[4];
            #pragma unroll
            for (int r = 0; r < 4; ++r) k1q[r] = K4[rf4[r] + half];
            #pragma unroll
            for (int nn = 0; nn < 4; ++nn) {
                int n = half*4 + nn;
                vfloat4 a = __builtin_amdgcn_mfma_f32_16x16x32_bf16(
                    eh, pwBv[(n*2 + 0)*64 + lane], vzero, 0, 0, 0);
                a = __builtin_amdgcn_mfma_f32_16x16x32_bf16(
                    eh2, pwBv[(n*2 + 1)*64 + lane], a, 0, 0, 0);
                int col = n*16 + c16;
                int s = col >> 5;
                int lp = ((col >> 3) & 3) << 4;
                int j = c16 & 7;
                float kv0 = (nn == 0) ? k1q[0].x : (nn == 1) ? k1q[0].y : (nn == 2) ? k1q[0].z : k1q[0].w;
                float kv1 = (nn == 0) ? k1q[1].x : (nn == 1) ? k1q[1].y : (nn == 2) ? k1q[1].z : k1q[1].w;
                float kv2 = (nn == 0) ? k1q[2].x : (nn == 1) ? k1q[2].y : (nn == 2) ? k1q[2].z : k1q[2].w;
                float kv3 = (nn == 0) ? k1q[3].x : (nn == 1) ? k1q[3].y : (nn == 2) ? k1q[3].z : k1q[3].w;
                hb[s*512 + (lp | (rowbase + 0))*8 + j] = bf16_rne(fmaxf(kv0 + a[0], 0.f));
                hb[s*512 + (lp | (rowbase + 1))*8 + j] = bf16_rne(fmaxf(kv1 + a[1], 0.f));
                hb[s*512 + (lp | (rowbase + 2))*8 + j] = bf16_rne(fmaxf(kv2 + a[2], 0.f));
                hb[s*512 + (lp | (rowbase + 3))*8 + j] = bf16_rne(fmaxf(kv3 + a[3], 0.f));
            }
        }
        asm volatile("s_waitcnt lgkmcnt(0)" ::: "memory");
        __builtin_amdgcn_sched_barrier(0);

        // h1 A-fragments once (k1q dead here)
        vshort8 ah[4];
        #pragma unroll
        for (int s = 0; s < 4; ++s) ah[s] = ((const vshort8*)hb)[s*64 + lane];

        // merged GEMM2 + pe2 + softmax; Vp gathers are float4 per half-batch
        #pragma unroll
        for (int half = 0; half < 2; ++half) {
            float4 vq[4];
            #pragma unroll
            for (int r = 0; r < 4; ++r) vq[r] = V4[rf4[r] + half];
            #pragma unroll
            for (int nn = 0; nn < 4; ++nn) {
                int n = half*4 + nn;
                vfloat4 ap = __builtin_amdgcn_mfma_f32_16x16x32_bf16(
                    eh, pwBv[((8 + n)*2 + 0)*64 + lane], vzero, 0, 0, 0);
                ap = __builtin_amdgcn_mfma_f32_16x16x32_bf16(
                    eh2, pwBv[((8 + n)*2 + 1)*64 + lane], ap, 0, 0, 0);
                vfloat4 a2 = vzero;
                #pragma unroll
                for (int s = 0; s < 4; ++s)
                    a2 = __builtin_amdgcn_mfma_f32_16x16x32_bf16(
                        ah[s], w2Bv[(n*4 + s)*64 + lane], a2, 0, 0, 0);

                float vvc[4];
                vvc[0] = (nn == 0) ? vq[0].x : (nn == 1) ? vq[0].y : (nn == 2) ? vq[0].z : vq[0].w;
                vvc[1] = (nn == 0) ? vq[1].x : (nn == 1) ? vq[1].y : (nn == 2) ? vq[1].z : vq[1].w;
                vvc[2] = (nn == 0) ? vq[2].x : (nn == 1) ? vq[2].y : (nn == 2) ? vq[2].z : vq[2].w;
                vvc[3] = (nn == 0) ? vq[3].x : (nn == 1) ? vq[3].y : (nn == 2) ? vq[3].z : vq[3].w;

                float hg = hgs[n*16 + c16];
                float mx = fmaxf(fmaxf(a2[0], a2[1]), fmaxf(a2[2], a2[3]));
                mx = fmaxf(mx, __shfl_xor(mx, 16));
                mx = fmaxf(mx, __shfl_xor(mx, 32));
                mx = fmaxf(mx, hg);
                float sum = 0.f, num = 0.f;
                #pragma unroll
                for (int r = 0; r < 4; ++r) {
                    float ev = __expf(a2[r] - mx);
                    float v = vvc[r] + ap[r];
                    sum += ev;
                    num = fmaf(ev, v, num);
                }
                sum += __shfl_xor(sum, 16); sum += __shfl_xor(sum, 32);
                num += __shfl_xor(num, 16); num += __shfl_xor(num, 32);
                float eg = __expf(hg - mx);
                sum += eg;
                num = fmaf(eg, vgs[n*16 + c16], num);
                if (g == 0) out[(b*NQ + q)*128 + n*16 + c16] = num / sum;
            }
        }
        asm volatile("s_waitcnt lgkmcnt(0)" ::: "memory");
        __builtin_amdgcn_sched_barrier(0);
    }
}

extern "C" void kernel_launch(void* const* d_in, const int* in_sizes, int n_in,
                              void* d_out, int out_size, void* d_ws, size_t ws_size,
                              hipStream_t stream) {
    const float* xyz_q  = (const float*)d_in[0];
    const float* lat    = (const float*)d_in[1];
    const float* xyz    = (const float*)d_in[2];
    const float* points = (const float*)d_in[3];
    const float* w_qs   = (const float*)d_in[4];
    const float* w_ks   = (const float*)d_in[5];
    const float* w_vs   = (const float*)d_in[6];
    const float* w_kg   = (const float*)d_in[7];
    const float* w_vg   = (const float*)d_in[8];
    const float* g_w1   = (const float*)d_in[9];
    const float* g_b1   = (const float*)d_in[10];
    const float* g_w2   = (const float*)d_in[11];
    const float* g_b2   = (const float*)d_in[12];  // cancels under softmax
    const float* pe_w   = (const float*)d_in[13];
    const float* pe_b   = (const float*)d_in[14];
    float* out = (float*)d_out;
    (void)g_b2;

    float* ws   = (float*)d_ws;
    float* Vp   = ws;                          // 2*4096*128
    float* K1c  = Vp  + NB*NPTS*DIM;           // 2*4096*128
    float* Wk1  = K1c + NB*NPTS*DIM;           // 128*128
    float* pwc  = Wk1 + DIM*DIM;               // 64*256
    float* c1   = pwc + 64*256;                // 256
    float* vg   = c1  + NB*DIM;                // 256
    float* h2g  = vg  + NB*DIM;                // 256
    int*   knn  = (int*)(h2g + NB*DIM);        // 2*8192*16
    ushort_t* pwf = (ushort_t*)(knn + NB*NQ*KNN);   // 16*2*64*8 bf16 = 32 KB
    ushort_t* w2f = pwf + 16*2*64*8;                // 32 KB
    int* cellcnt  = (int*)(w2f + 32*64*8);          // 2*1024
    int* cellstart = cellcnt + NB*NCELL;            // 2*1025
    int* cursor    = cellstart + NB*(NCELL+1);      // 2*1024
    int* sidx      = cursor + NB*NCELL;             // 2*4096
    float2* sxy    = (float2*)(sidx + NB*NPTS);     // 2*4096 float2

    hipMemsetAsync(cellcnt, 0, NB*NCELL*sizeof(int), stream);
    wprod_k<<<192, 128, 0, stream>>>(w_ks, g_w1, pe_w, Wk1, pwc);
    pack_k<<<8, 256, 0, stream>>>(pwc, 64, 256, 16, 2, pwf);
    pack_k<<<8, 256, 0, stream>>>(g_w2, 128, 128, 8, 4, w2f);
    prep_global_k<<<1, 256, 0, stream>>>(lat, w_qs, w_kg, w_vg,
                                         g_w1, g_b1, g_w2, pe_b, c1, vg, h2g);
    cellcount_k<<<NB*NPTS/256, 256, 0, stream>>>(xyz, cellcnt);
    prefix_k<<<NB, 1024, 0, stream>>>(cellcnt, cellstart, cursor);
    scatter_k<<<NB*NPTS/256, 256, 0, stream>>>(xyz, cursor, sxy, sidx);
    kv_proj_k<<<NB*NPTS/KVROWS, 256, 0, stream>>>(points, Wk1, w_vs, pe_b, c1, K1c, Vp);
    knn_k<<<NB*NQ/4, 256, 0, stream>>>(xyz_q, sxy, sidx, cellstart, knn);
    fuse_k<<<NB*NQ/16, 256, 0, stream>>>(xyz_q, xyz, K1c, Vp, knn, vg, h2g,
                                         pwf, w2f, out);
}

// Round 11
// 168.036 us; speedup vs baseline: 1.1647x; 1.1021x over previous
//
#include <hip/hip_runtime.h>
#include <cstdint>

#define DIM   128
#define KNN   16
#define NB    2
#define NQ    8192
#define NPTS  4096
#define KVROWS 16
#define GRID  32
#define NCELL (GRID*GRID)
#define CAP   384

typedef unsigned short ushort_t;
typedef short vshort8 __attribute__((ext_vector_type(8)));
typedef float vfloat4 __attribute__((ext_vector_type(4)));

__device__ __forceinline__ ushort_t bf16_rne(float f) {
    unsigned u = __float_as_uint(f);
    unsigned r = u + 0x7FFFu + ((u >> 16) & 1u);
    return (ushort_t)(r >> 16);
}
__device__ __forceinline__ int cell_of(float x) {
    int c = (int)(x * 32.0f);
    return min(max(c, 0), GRID - 1);
}
__device__ __forceinline__ float f4_at(float4 v, int i) {
    return (i == 0) ? v.x : (i == 1) ? v.y : (i == 2) ? v.z : v.w;
}

// emb A-fragment for k = g*8 + j (k < 32)
__device__ __forceinline__ vshort8 emb_lo(float pd0, float pd1, float pd2, int g) {
    vshort8 eh;
    int k0 = g*8;
    #pragma unroll
    for (int j = 0; j < 8; ++j) {
        int k = k0 + j;
        float v;
        if (k < 3) {
            v = (k == 0) ? pd0 : (k == 1 ? pd1 : pd2);
        } else {
            int m = k - 3; int fi = m / 6; int rem = m - fi*6;
            int comp = (rem < 3) ? rem : rem - 3;
            float pdc = (comp == 0) ? pd0 : (comp == 1 ? pd1 : pd2);
            float fr = (fi == 0) ? 1.0f : (fi == 1) ? 8.75f : (fi == 2) ? 16.5f
                     : (fi == 3) ? 24.25f : 32.0f;
            float arg = pdc * fr;
            v = (rem < 3) ? __sinf(arg) : __cosf(arg);
        }
        eh[j] = (short)bf16_rne(v);
    }
    return eh;
}

// ---------------- W-products: Wk1 = w_ks@g_w1 ; pwc = [pe_w@g_w1 | pe_w] (64x256, rows 33..63 zero) ----------------
__global__ __launch_bounds__(128) void wprod_k(
    const float* __restrict__ w_ks, const float* __restrict__ g_w1,
    const float* __restrict__ pe_w,
    float* __restrict__ Wk1, float* __restrict__ pwc)
{
    int f = threadIdx.x; int blk = blockIdx.x;
    if (blk < 128) {
        float acc = 0.f;
        for (int t = 0; t < 128; ++t) acc = fmaf(w_ks[blk*128 + t], g_w1[t*128 + f], acc);
        Wk1[blk*128 + f] = acc;
    } else {
        int r = blk - 128;                      // 0..63
        for (int h = 0; h < 2; ++h) {
            int col = f + h*128;
            float v = 0.f;
            if (r < 33) {
                if (col < 128) {
                    float a = 0.f;
                    for (int t = 0; t < 128; ++t) a = fmaf(pe_w[r*128 + t], g_w1[t*128 + col], a);
                    v = a;
                } else {
                    v = pe_w[r*128 + (col - 128)];
                }
            }
            pwc[r*256 + col] = v;
        }
    }
}

// ---------------- pack f32 [K][ncols] into MFMA B-fragments, single bf16 ----------------
__global__ __launch_bounds__(256) void pack_k(
    const float* __restrict__ src, int K, int ncols, int NT, int KS,
    ushort_t* __restrict__ dst)
{
    int gid = blockIdx.x*256 + threadIdx.x;
    int total = NT*KS*64;
    if (gid >= total) return;
    int lane = gid & 63; int c = gid >> 6;
    int s = c % KS; int n = c / KS;
    int k0 = s*32 + ((lane >> 4) << 3);
    int col = n*16 + (lane & 15);
    vshort8 v;
    #pragma unroll
    for (int i = 0; i < 8; ++i) {
        int k = k0 + i;
        float f = (k < K) ? src[k*ncols + col] : 0.f;
        v[i] = (short)bf16_rne(f);
    }
    *(vshort8*)(dst + gid*8) = v;
}

// ---------------- per-batch global branch ----------------
__global__ __launch_bounds__(256) void prep_global_k(
    const float* __restrict__ lat, const float* __restrict__ w_qs,
    const float* __restrict__ w_kg, const float* __restrict__ w_vg,
    const float* __restrict__ g_w1, const float* __restrict__ g_b1,
    const float* __restrict__ g_w2, const float* __restrict__ pe_b,
    float* __restrict__ c1_out, float* __restrict__ vg_out, float* __restrict__ h2g_out)
{
    __shared__ float qs[NB][DIM];
    __shared__ float hg[NB][DIM];
    __shared__ float h1g[NB][DIM];
    int t = threadIdx.x; int b = t >> 7; int f = t & 127;
    float aq = 0.f, ak = 0.f, av = 0.f;
    for (int c = 0; c < DIM; ++c) {
        float l = lat[b*DIM + c];
        aq = fmaf(l, w_qs[c*DIM + f], aq);
        ak = fmaf(l, w_kg[c*DIM + f], ak);
        av = fmaf(l, w_vg[c*DIM + f], av);
    }
    vg_out[b*DIM + f] = av;
    qs[b][f] = aq + pe_b[f];
    hg[b][f] = aq - ak;
    __syncthreads();
    float acc = g_b1[f], acch = g_b1[f];
    for (int c = 0; c < DIM; ++c) {
        float w = g_w1[c*DIM + f];
        acc  = fmaf(qs[b][c], w, acc);
        acch = fmaf(hg[b][c], w, acch);
    }
    c1_out[b*DIM + f] = acc;
    h1g[b][f] = fmaxf(acch, 0.f);
    __syncthreads();
    float acc2 = 0.f;                       // b2 dropped (softmax-invariant)
    for (int c = 0; c < DIM; ++c) acc2 = fmaf(h1g[b][c], g_w2[c*DIM + f], acc2);
    h2g_out[b*DIM + f] = acc2;
}

// ---------------- K1c = c1 - points@Wk1 ; Vp' = points@w_vs + pe_b ----------------
// fragment-major row layout: element (row, col) at row*128 + (col&15)*8 + (col>>4)
__global__ __launch_bounds__(256) void kv_proj_k(
    const float* __restrict__ points, const float* __restrict__ Wk1,
    const float* __restrict__ w_vs, const float* __restrict__ pe_b,
    const float* __restrict__ c1_,
    float* __restrict__ K1c, float* __restrict__ Vp)
{
    __shared__ __align__(16) float pts[KVROWS*DIM];
    int t = threadIdx.x;
    int r0 = blockIdx.x * KVROWS;
    int b = r0 >> 12;
    #pragma unroll
    for (int k = 0; k < KVROWS*DIM/256; ++k) {
        int e = t + k*256;
        pts[e] = points[r0*DIM + e];
    }
    __syncthreads();
    int f = t & 127; int mat = t >> 7;
    const float* W = mat ? w_vs : Wk1;
    float* O = mat ? Vp : K1c;
    float addv = mat ? pe_b[f] : c1_[b*DIM + f];
    float sgn  = mat ? 1.f : -1.f;
    int fc = (f & 15)*8 + (f >> 4);
    float acc[KVROWS];
    #pragma unroll
    for (int r = 0; r < KVROWS; ++r) acc[r] = 0.f;
    const float4* pts4 = reinterpret_cast<const float4*>(pts);
    for (int c4 = 0; c4 < DIM/4; ++c4) {
        float w0 = W[(c4*4+0)*DIM + f];
        float w1 = W[(c4*4+1)*DIM + f];
        float w2 = W[(c4*4+2)*DIM + f];
        float w3 = W[(c4*4+3)*DIM + f];
        #pragma unroll
        for (int r = 0; r < KVROWS; ++r) {
            float4 p = pts4[r*(DIM/4) + c4];
            acc[r] = fmaf(p.x, w0, acc[r]);
            acc[r] = fmaf(p.y, w1, acc[r]);
            acc[r] = fmaf(p.z, w2, acc[r]);
            acc[r] = fmaf(p.w, w3, acc[r]);
        }
    }
    #pragma unroll
    for (int r = 0; r < KVROWS; ++r) O[(r0 + r)*DIM + fc] = fmaf(sgn, acc[r], addv);
}

// ---------------- spatial binning: count / scan / scatter ----------------
__global__ __launch_bounds__(256) void cellcount_k(
    const float* __restrict__ xyz, int* __restrict__ cnt)
{
    int gid = blockIdx.x*256 + threadIdx.x;
    int b = gid >> 12; int n = gid & (NPTS - 1);
    const float* p = xyz + (b*NPTS + n)*3;
    int cx = cell_of(p[0]);
    int cy = cell_of(p[1]);
    atomicAdd(&cnt[b*NCELL + cy*GRID + cx], 1);
}

__global__ __launch_bounds__(1024) void prefix_k(
    const int* __restrict__ cnt, int* __restrict__ cell_start,
    int* __restrict__ cursor)
{
    __shared__ int s[NCELL];
    int b = blockIdx.x; int t = threadIdx.x;
    int v = cnt[b*NCELL + t];
    s[t] = v;
    __syncthreads();
    for (int off = 1; off < NCELL; off <<= 1) {
        int add = (t >= off) ? s[t - off] : 0;
        __syncthreads();
        s[t] += add;
        __syncthreads();
    }
    int incl = s[t];
    cell_start[b*(NCELL+1) + t] = incl - v;
    cursor[b*NCELL + t] = incl - v;
    if (t == NCELL - 1) cell_start[b*(NCELL+1) + NCELL] = incl;
}

__global__ __launch_bounds__(256) void scatter_k(
    const float* __restrict__ xyz, int* __restrict__ cursor,
    float2* __restrict__ sxy, int* __restrict__ sidx)
{
    int gid = blockIdx.x*256 + threadIdx.x;
    int b = gid >> 12; int n = gid & (NPTS - 1);
    const float* p = xyz + (b*NPTS + n)*3;
    float x = p[0], y = p[1];
    int cx = cell_of(x);
    int cy = cell_of(y);
    int slot = atomicAdd(&cursor[b*NCELL + cy*GRID + cx], 1);
    sxy[b*NPTS + slot] = make_float2(x, y);
    sidx[b*NPTS + slot] = n;
}

// ---------------- exact kNN: grid-binned candidates + 16x wave-argmin ----------------
__global__ __launch_bounds__(256) void knn_k(
    const float* __restrict__ xyz_q, const float2* __restrict__ sxy,
    const int* __restrict__ sidx, const int* __restrict__ cstart,
    int* __restrict__ knn_out)
{
    __shared__ float cand_d[4][CAP];
    __shared__ int   cand_i[4][CAP];
    int t = threadIdx.x; int wid = t >> 6, lane = t & 63;
    int bx = blockIdx.x; int b = bx >> 11; int q = (bx & 2047)*4 + wid;
    float xq = xyz_q[(b*NQ + q)*2 + 0];
    float yq = xyz_q[(b*NQ + q)*2 + 1];
    int cx = cell_of(xq), cy = cell_of(yq);
    const int* cs_b = cstart + b*(NCELL+1);
    float* cd = cand_d[wid]; int* ci = cand_i[wid];
    const float INF = 3.4e38f;
    const float CS = 1.0f/32.0f;
    int* outp = knn_out + (b*NQ + q)*KNN;
    int myIdx = 0;

    for (int R = 2; R < 9; ++R) {
        int x0 = max(cx-R, 0), x1 = min(cx+R, GRID-1);
        int y0 = max(cy-R, 0), y1 = min(cy+R, GRID-1);
        int cnt = 0;
        for (int ry = y0; ry <= y1; ++ry) {
            int s0 = cs_b[ry*GRID + x0];
            int e0 = cs_b[ry*GRID + x1 + 1];
            for (int o = s0 + lane; o < e0; o += 64) {
                float2 p = sxy[b*NPTS + o];
                float dx = __fadd_rn(xq, -p.x);
                float dy = __fadd_rn(yq, -p.y);
                float d = __fadd_rn(__fmul_rn(dx, dx), __fmul_rn(dy, dy));
                int slot = cnt + (o - s0);
                if (slot < CAP) { cd[slot] = d; ci[slot] = o; }
            }
            cnt += e0 - s0;
        }
        asm volatile("s_waitcnt lgkmcnt(0)" ::: "memory");
        __builtin_amdgcn_sched_barrier(0);

        float dr[6];
        #pragma unroll
        for (int k = 0; k < 6; ++k)
            dr[k] = (lane + k*64 < cnt) ? cd[lane + k*64] : INF;
        float d16 = INF;
        for (int r = 0; r < KNN; ++r) {
            float v = dr[0]; int s = lane;
            #pragma unroll
            for (int k = 1; k < 6; ++k)
                if (dr[k] < v) { v = dr[k]; s = lane + k*64; }
            #pragma unroll
            for (int off = 32; off >= 1; off >>= 1) {
                float ov = __shfl_xor(v, off);
                int   os = __shfl_xor(s, off);
                if (ov < v || (ov == v && os < s)) { v = ov; s = os; }
            }
            if (lane == r) myIdx = sidx[b*NPTS + ci[s]];
            if ((s & 63) == lane) {
                int k = s >> 6;
                if      (k == 0) dr[0] = INF;
                else if (k == 1) dr[1] = INF;
                else if (k == 2) dr[2] = INF;
                else if (k == 3) dr[3] = INF;
                else if (k == 4) dr[4] = INF;
                else             dr[5] = INF;
            }
            d16 = v;
        }
        float bl = (x0 > 0)      ? (xq - (float)x0*CS)       : INF;
        float br = (x1 < GRID-1) ? ((float)(x1+1)*CS - xq)   : INF;
        float bb = (y0 > 0)      ? (yq - (float)y0*CS)       : INF;
        float bt = (y1 < GRID-1) ? ((float)(y1+1)*CS - yq)   : INF;
        float safe = fminf(fminf(bl, br), fminf(bb, bt)) - 2e-6f;
        bool whole = (safe > 1e8f);
        bool ok = (cnt >= KNN) && (cnt <= CAP) && (whole || d16 <= safe*safe);
        if (ok || R == 8) {
            if (lane < KNN) outp[lane] = myIdx;
            break;
        }
    }
}

// ---------------- fused MFMA kernel v11: 2 queries/wave lockstep (ILP, B-frag reuse) ----------------
// 512 threads = 8 waves, uncapped regs (2 waves/SIMD natural). Each wave processes
// 8 queries as 4 pairs; the pair shares every B-fragment load and provides 2
// independent dependency chains per latency window. No asm fences (compiler
// auto-waitcnt handles the h1 LDS RAW dep; per-query h1 buffers avoid WAR).
__global__ __launch_bounds__(512, 2) void fuse_k(
    const float* __restrict__ xyz_q, const float* __restrict__ xyz,
    const float* __restrict__ K1c, const float* __restrict__ Vp,
    const int* __restrict__ knn_idx,
    const float* __restrict__ vg_, const float* __restrict__ h2g_,
    const ushort_t* __restrict__ pwf, const ushort_t* __restrict__ w2f,
    float* __restrict__ out)
{
    __shared__ __align__(16) ushort_t w2B[32*512];     // 32 KB
    __shared__ __align__(16) ushort_t h1b[8][2][2048]; // 64 KB (per-wave, per-pair-slot)
    __shared__ float hgs[128], vgs[128];

    int t = threadIdx.x, lane = t & 63, wid = t >> 6;
    int bx = blockIdx.x; int b = bx >> 7; int qbase = (bx & 127) * 64;

    {   // stage w2 frags once per block (32 KB) + per-batch vectors
        const int4* s2 = (const int4*)w2f;  int4* d2 = (int4*)w2B;
        #pragma unroll
        for (int i = 0; i < 4; ++i) d2[t + i*512] = s2[t + i*512];
        if (t < 128) {
            hgs[t] = h2g_[b*128 + t];
            vgs[t] = vg_[b*128 + t];
        }
    }
    __syncthreads();

    int c16 = lane & 15, g = lane >> 4, rowbase = g*4;
    ushort_t* hba = h1b[wid][0];
    ushort_t* hbb = h1b[wid][1];
    const vshort8* pwBv = (const vshort8*)pwf;         // global, L1/L2-resident
    const vshort8* w2Bv = (const vshort8*)w2B;
    const float4* K4 = (const float4*)K1c;
    const float4* V4 = (const float4*)Vp;
    const vfloat4 vzero = (vfloat4){0.f, 0.f, 0.f, 0.f};

    #pragma unroll 1
    for (int pi = 0; pi < 4; ++pi) {
        int qa = qbase + wid*8 + pi*2;
        int qb = qa + 1;
        // ---- per-query setup (independent chains) ----
        float xqa = xyz_q[(b*NQ + qa)*2 + 0], yqa = xyz_q[(b*NQ + qa)*2 + 1];
        float xqb = xyz_q[(b*NQ + qb)*2 + 0], yqb = xyz_q[(b*NQ + qb)*2 + 1];
        int ia = knn_idx[(b*NQ + qa)*KNN + c16];
        int ib = knn_idx[(b*NQ + qb)*KNN + c16];
        const float* pa = xyz + (b*NPTS + ia)*3;
        const float* pb = xyz + (b*NPTS + ib)*3;
        float a0 = xqa - pa[0], a1 = yqa - pa[1], a2 = pa[2];
        float b0 = xqb - pb[0], b1 = yqb - pb[1], b2 = pb[2];
        int rfa[4], rfb[4];
        #pragma unroll
        for (int r = 0; r < 4; ++r) {
            rfa[r] = (b*NPTS + __shfl(ia, rowbase + r))*32 + c16*2;
            rfb[r] = (b*NPTS + __shfl(ib, rowbase + r))*32 + c16*2;
        }
        vshort8 eha = emb_lo(a0, a1, a2, g);
        vshort8 ehb = emb_lo(b0, b1, b2, g);
        vshort8 eha2 = (vshort8){0,0,0,0,0,0,0,0};
        vshort8 ehb2 = (vshort8){0,0,0,0,0,0,0,0};
        if (g == 0) {
            eha2[0] = (short)bf16_rne(__cosf(32.0f * a2));
            ehb2[0] = (short)bf16_rne(__cosf(32.0f * b2));
        }

        // ---- pe1 + h1 epilogue (both queries share B-frags) ----
        #pragma unroll
        for (int half = 0; half < 2; ++half) {
            float4 ka0 = K4[rfa[0] + half], ka1 = K4[rfa[1] + half];
            float4 ka2 = K4[rfa[2] + half], ka3 = K4[rfa[3] + half];
            float4 kb0 = K4[rfb[0] + half], kb1 = K4[rfb[1] + half];
            float4 kb2 = K4[rfb[2] + half], kb3 = K4[rfb[3] + half];
            #pragma unroll
            for (int nn = 0; nn < 4; ++nn) {
                int n = half*4 + nn;
                vshort8 bh0 = pwBv[(n*2 + 0)*64 + lane];
                vshort8 bh1 = pwBv[(n*2 + 1)*64 + lane];
                vfloat4 aa = __builtin_amdgcn_mfma_f32_16x16x32_bf16(eha, bh0, vzero, 0, 0, 0);
                aa = __builtin_amdgcn_mfma_f32_16x16x32_bf16(eha2, bh1, aa, 0, 0, 0);
                vfloat4 ab = __builtin_amdgcn_mfma_f32_16x16x32_bf16(ehb, bh0, vzero, 0, 0, 0);
                ab = __builtin_amdgcn_mfma_f32_16x16x32_bf16(ehb2, bh1, ab, 0, 0, 0);
                int col = n*16 + c16;
                int s = col >> 5;
                int lp = ((col >> 3) & 3) << 4;
                int base = s*512 + lp*8 + (c16 & 7);
                hba[base + (rowbase + 0)*8] = bf16_rne(fmaxf(f4_at(ka0, nn) + aa[0], 0.f));
                hba[base + (rowbase + 1)*8] = bf16_rne(fmaxf(f4_at(ka1, nn) + aa[1], 0.f));
                hba[base + (rowbase + 2)*8] = bf16_rne(fmaxf(f4_at(ka2, nn) + aa[2], 0.f));
                hba[base + (rowbase + 3)*8] = bf16_rne(fmaxf(f4_at(ka3, nn) + aa[3], 0.f));
                hbb[base + (rowbase + 0)*8] = bf16_rne(fmaxf(f4_at(kb0, nn) + ab[0], 0.f));
                hbb[base + (rowbase + 1)*8] = bf16_rne(fmaxf(f4_at(kb1, nn) + ab[1], 0.f));
                hbb[base + (rowbase + 2)*8] = bf16_rne(fmaxf(f4_at(kb2, nn) + ab[2], 0.f));
                hbb[base + (rowbase + 3)*8] = bf16_rne(fmaxf(f4_at(kb3, nn) + ab[3], 0.f));
            }
        }

        // ---- h1 A-fragments (compiler inserts the lgkmcnt wait for the RAW dep) ----
        vshort8 aha[4], ahb[4];
        #pragma unroll
        for (int s = 0; s < 4; ++s) {
            aha[s] = ((const vshort8*)hba)[s*64 + lane];
            ahb[s] = ((const vshort8*)hbb)[s*64 + lane];
        }

        // ---- merged GEMM2 + pe2 + softmax, per 16-feature group ----
        #pragma unroll
        for (int half = 0; half < 2; ++half) {
            float4 va0 = V4[rfa[0] + half], va1 = V4[rfa[1] + half];
            float4 va2 = V4[rfa[2] + half], va3 = V4[rfa[3] + half];
            float4 vb0 = V4[rfb[0] + half], vb1 = V4[rfb[1] + half];
            float4 vb2 = V4[rfb[2] + half], vb3 = V4[rfb[3] + half];
            #pragma unroll
            for (int nn = 0; nn < 4; ++nn) {
                int n = half*4 + nn;
                vshort8 p0 = pwBv[((8 + n)*2 + 0)*64 + lane];
                vshort8 p1 = pwBv[((8 + n)*2 + 1)*64 + lane];
                vfloat4 apa = __builtin_amdgcn_mfma_f32_16x16x32_bf16(eha, p0, vzero, 0, 0, 0);
                apa = __builtin_amdgcn_mfma_f32_16x16x32_bf16(eha2, p1, apa, 0, 0, 0);
                vfloat4 apb = __builtin_amdgcn_mfma_f32_16x16x32_bf16(ehb, p0, vzero, 0, 0, 0);
                apb = __builtin_amdgcn_mfma_f32_16x16x32_bf16(ehb2, p1, apb, 0, 0, 0);
                vfloat4 sa = vzero, sb = vzero;
                #pragma unroll
                for (int s = 0; s < 4; ++s) {
                    vshort8 wv = w2Bv[(n*4 + s)*64 + lane];
                    sa = __builtin_amdgcn_mfma_f32_16x16x32_bf16(aha[s], wv, sa, 0, 0, 0);
                    sb = __builtin_amdgcn_mfma_f32_16x16x32_bf16(ahb[s], wv, sb, 0, 0, 0);
                }
                float hg = hgs[n*16 + c16];
                float vgv = vgs[n*16 + c16];
                // query A softmax
                {
                    float mx = fmaxf(fmaxf(sa[0], sa[1]), fmaxf(sa[2], sa[3]));
                    mx = fmaxf(mx, __shfl_xor(mx, 16));
                    mx = fmaxf(mx, __shfl_xor(mx, 32));
                    mx = fmaxf(mx, hg);
                    float vv0 = f4_at(va0, nn), vv1 = f4_at(va1, nn);
                    float vv2 = f4_at(va2, nn), vv3 = f4_at(va3, nn);
                    float e0 = __expf(sa[0] - mx), e1 = __expf(sa[1] - mx);
                    float e2 = __expf(sa[2] - mx), e3 = __expf(sa[3] - mx);
                    float sum = e0 + e1 + e2 + e3;
                    float num = e0*(vv0 + apa[0]) + e1*(vv1 + apa[1])
                              + e2*(vv2 + apa[2]) + e3*(vv3 + apa[3]);
                    sum += __shfl_xor(sum, 16); sum += __shfl_xor(sum, 32);
                    num += __shfl_xor(num, 16); num += __shfl_xor(num, 32);
                    float eg = __expf(hg - mx);
                    sum += eg;
                    num = fmaf(eg, vgv, num);
                    if (g == 0) out[(b*NQ + qa)*128 + n*16 + c16] = num / sum;
                }
                // query B softmax
                {
                    float mx = fmaxf(fmaxf(sb[0], sb[1]), fmaxf(sb[2], sb[3]));
                    mx = fmaxf(mx, __shfl_xor(mx, 16));
                    mx = fmaxf(mx, __shfl_xor(mx, 32));
                    mx = fmaxf(mx, hg);
                    float vv0 = f4_at(vb0, nn), vv1 = f4_at(vb1, nn);
                    float vv2 = f4_at(vb2, nn), vv3 = f4_at(vb3, nn);
                    float e0 = __expf(sb[0] - mx), e1 = __expf(sb[1] - mx);
                    float e2 = __expf(sb[2] - mx), e3 = __expf(sb[3] - mx);
                    float sum = e0 + e1 + e2 + e3;
                    float num = e0*(vv0 + apb[0]) + e1*(vv1 + apb[1])
                              + e2*(vv2 + apb[2]) + e3*(vv3 + apb[3]);
                    sum += __shfl_xor(sum, 16); sum += __shfl_xor(sum, 32);
                    num += __shfl_xor(num, 16); num += __shfl_xor(num, 32);
                    float eg = __expf(hg - mx);
                    sum += eg;
                    num = fmaf(eg, vgv, num);
                    if (g == 0) out[(b*NQ + qb)*128 + n*16 + c16] = num / sum;
                }
            }
        }
    }
}

extern "C" void kernel_launch(void* const* d_in, const int* in_sizes, int n_in,
                              void* d_out, int out_size, void* d_ws, size_t ws_size,
                              hipStream_t stream) {
    const float* xyz_q  = (const float*)d_in[0];
    const float* lat    = (const float*)d_in[1];
    const float* xyz    = (const float*)d_in[2];
    const float* points = (const float*)d_in[3];
    const float* w_qs   = (const float*)d_in[4];
    const float* w_ks   = (const float*)d_in[5];
    const float* w_vs   = (const float*)d_in[6];
    const float* w_kg   = (const float*)d_in[7];
    const float* w_vg   = (const float*)d_in[8];
    const float* g_w1   = (const float*)d_in[9];
    const float* g_b1   = (const float*)d_in[10];
    const float* g_w2   = (const float*)d_in[11];
    const float* g_b2   = (const float*)d_in[12];  // cancels under softmax
    const float* pe_w   = (const float*)d_in[13];
    const float* pe_b   = (const float*)d_in[14];
    float* out = (float*)d_out;
    (void)g_b2;

    float* ws   = (float*)d_ws;
    float* Vp   = ws;                          // 2*4096*128
    float* K1c  = Vp  + NB*NPTS*DIM;           // 2*4096*128
    float* Wk1  = K1c + NB*NPTS*DIM;           // 128*128
    float* pwc  = Wk1 + DIM*DIM;               // 64*256
    float* c1   = pwc + 64*256;                // 256
    float* vg   = c1  + NB*DIM;                // 256
    float* h2g  = vg  + NB*DIM;                // 256
    int*   knn  = (int*)(h2g + NB*DIM);        // 2*8192*16
    ushort_t* pwf = (ushort_t*)(knn + NB*NQ*KNN);   // 16*2*64*8 bf16 = 32 KB
    ushort_t* w2f = pwf + 16*2*64*8;                // 32 KB
    int* cellcnt  = (int*)(w2f + 32*64*8);          // 2*1024
    int* cellstart = cellcnt + NB*NCELL;            // 2*1025
    int* cursor    = cellstart + NB*(NCELL+1);      // 2*1024
    int* sidx      = cursor + NB*NCELL;             // 2*4096
    float2* sxy    = (float2*)(sidx + NB*NPTS);     // 2*4096 float2

    hipMemsetAsync(cellcnt, 0, NB*NCELL*sizeof(int), stream);
    wprod_k<<<192, 128, 0, stream>>>(w_ks, g_w1, pe_w, Wk1, pwc);
    pack_k<<<8, 256, 0, stream>>>(pwc, 64, 256, 16, 2, pwf);
    pack_k<<<8, 256, 0, stream>>>(g_w2, 128, 128, 8, 4, w2f);
    prep_global_k<<<1, 256, 0, stream>>>(lat, w_qs, w_kg, w_vg,
                                         g_w1, g_b1, g_w2, pe_b, c1, vg, h2g);
    cellcount_k<<<NB*NPTS/256, 256, 0, stream>>>(xyz, cellcnt);
    prefix_k<<<NB, 1024, 0, stream>>>(cellcnt, cellstart, cursor);
    scatter_k<<<NB*NPTS/256, 256, 0, stream>>>(xyz, cursor, sxy, sidx);
    kv_proj_k<<<NB*NPTS/KVROWS, 256, 0, stream>>>(points, Wk1, w_vs, pe_b, c1, K1c, Vp);
    knn_k<<<NB*NQ/4, 256, 0, stream>>>(xyz_q, sxy, sidx, cellstart, knn);
    fuse_k<<<NB*NQ/64, 512, 0, stream>>>(xyz_q, xyz, K1c, Vp, knn, vg, h2g,
                                         pwf, w2f, out);
}

// Round 12
// 141.675 us; speedup vs baseline: 1.3815x; 1.1861x over previous
//
#include <hip/hip_runtime.h>
#include <cstdint>

#define DIM   128
#define KNN   16
#define NB    2
#define NQ    8192
#define NPTS  4096
#define KVROWS 16
#define GRID  32
#define NCELL (GRID*GRID)
#define CAP   384

typedef unsigned short ushort_t;
typedef short vshort8 __attribute__((ext_vector_type(8)));
typedef float vfloat4 __attribute__((ext_vector_type(4)));

__device__ __forceinline__ ushort_t bf16_rne(float f) {
    unsigned u = __float_as_uint(f);
    unsigned r = u + 0x7FFFu + ((u >> 16) & 1u);
    return (ushort_t)(r >> 16);
}
__device__ __forceinline__ int cell_of(float x) {
    int c = (int)(x * 32.0f);
    return min(max(c, 0), GRID - 1);
}

// pack f32 [K][ncols] -> MFMA B-fragments (single bf16), device body
__device__ __forceinline__ void pack_body(
    const float* __restrict__ src, int K, int ncols, int NT, int KS,
    ushort_t* __restrict__ dst, int gid)
{
    int total = NT*KS*64;
    if (gid >= total) return;
    int lane = gid & 63; int c = gid >> 6;
    int s = c % KS; int n = c / KS;
    int k0 = s*32 + ((lane >> 4) << 3);
    int col = n*16 + (lane & 15);
    vshort8 v;
    #pragma unroll
    for (int i = 0; i < 8; ++i) {
        int k = k0 + i;
        float f = (k < K) ? src[k*ncols + col] : 0.f;
        v[i] = (short)bf16_rne(f);
    }
    *(vshort8*)(dst + gid*8) = v;
}

// ---------------- pre1: Wk1 + pwc (wprod) || cellcount.  160 blocks x 256 ----------------
__global__ __launch_bounds__(256) void pre1_k(
    const float* __restrict__ w_ks, const float* __restrict__ g_w1,
    const float* __restrict__ pe_w, const float* __restrict__ xyz,
    float* __restrict__ Wk1, float* __restrict__ pwc, int* __restrict__ cellcnt)
{
    int t = threadIdx.x; int bx = blockIdx.x;
    if (bx < 64) {                       // Wk1: rows 2bx+(t>>7)
        int row = bx*2 + (t >> 7); int f = t & 127;
        float acc = 0.f;
        for (int c = 0; c < 128; ++c) acc = fmaf(w_ks[row*128 + c], g_w1[c*128 + f], acc);
        Wk1[row*128 + f] = acc;
    } else if (bx < 128) {               // pwc: row bx-64, col t (0..255)
        int r = bx - 64; int col = t;
        float v = 0.f;
        if (r < 33) {
            if (col < 128) {
                float a = 0.f;
                for (int c = 0; c < 128; ++c) a = fmaf(pe_w[r*128 + c], g_w1[c*128 + col], a);
                v = a;
            } else {
                v = pe_w[r*128 + (col - 128)];
            }
        }
        pwc[r*256 + col] = v;
    } else {                             // cellcount: 32 blocks
        int gid = (bx - 128)*256 + t;
        int b = gid >> 12; int n = gid & (NPTS - 1);
        const float* p = xyz + (b*NPTS + n)*3;
        atomicAdd(&cellcnt[b*NCELL + cell_of(p[1])*GRID + cell_of(p[0])], 1);
    }
}

// ---------------- pre2: pack pwf || pack w2f || prefix || prep_global.  15 blocks x 256 ----------------
__global__ __launch_bounds__(256) void pre2_k(
    const float* __restrict__ pwc, const float* __restrict__ g_w2,
    const int* __restrict__ cnt,
    const float* __restrict__ lat, const float* __restrict__ w_qs,
    const float* __restrict__ w_kg, const float* __restrict__ w_vg,
    const float* __restrict__ g_w1, const float* __restrict__ g_b1,
    const float* __restrict__ pe_b,
    ushort_t* __restrict__ pwf, ushort_t* __restrict__ w2f,
    int* __restrict__ cell_start, int* __restrict__ cursor,
    float* __restrict__ c1_out, float* __restrict__ vg_out, float* __restrict__ h2g_out)
{
    __shared__ int ss[256];
    __shared__ float qs[NB][DIM];
    __shared__ float hgx[NB][DIM];
    __shared__ float h1gx[NB][DIM];
    int t = threadIdx.x; int bx = blockIdx.x;
    if (bx < 4) {                        // pack pwf: 16 KB (KS=1, K=32)
        pack_body(pwc, 32, 256, 16, 1, pwf, bx*256 + t);
    } else if (bx < 12) {                // pack w2f: 32 KB
        pack_body(g_w2, 128, 128, 8, 4, w2f, (bx - 4)*256 + t);
    } else if (bx < 14) {                // prefix scan, batch b = bx-12, 4 cells/thread
        int b = bx - 12;
        int v0 = cnt[b*NCELL + t*4 + 0];
        int v1 = cnt[b*NCELL + t*4 + 1];
        int v2 = cnt[b*NCELL + t*4 + 2];
        int v3 = cnt[b*NCELL + t*4 + 3];
        int p0 = v0, p1 = p0 + v1, p2 = p1 + v2, p3 = p2 + v3;
        ss[t] = p3;
        __syncthreads();
        for (int off = 1; off < 256; off <<= 1) {
            int add = (t >= off) ? ss[t - off] : 0;
            __syncthreads();
            ss[t] += add;
            __syncthreads();
        }
        int excl = ss[t] - p3;
        int* cs = cell_start + b*(NCELL + 1);
        int* cu = cursor + b*NCELL;
        cs[t*4 + 0] = excl;        cu[t*4 + 0] = excl;
        cs[t*4 + 1] = excl + p0;   cu[t*4 + 1] = excl + p0;
        cs[t*4 + 2] = excl + p1;   cu[t*4 + 2] = excl + p1;
        cs[t*4 + 3] = excl + p2;   cu[t*4 + 3] = excl + p2;
        if (t == 255) cs[NCELL] = ss[255];
    } else {                             // prep_global (1 block)
        int b = t >> 7; int f = t & 127;
        float aq = 0.f, ak = 0.f, av = 0.f;
        for (int c = 0; c < DIM; ++c) {
            float l = lat[b*DIM + c];
            aq = fmaf(l, w_qs[c*DIM + f], aq);
            ak = fmaf(l, w_kg[c*DIM + f], ak);
            av = fmaf(l, w_vg[c*DIM + f], av);
        }
        vg_out[b*DIM + f] = av;
        qs[b][f] = aq + pe_b[f];
        hgx[b][f] = aq - ak;
        __syncthreads();
        float acc = g_b1[f], acch = g_b1[f];
        for (int c = 0; c < DIM; ++c) {
            float w = g_w1[c*DIM + f];
            acc  = fmaf(qs[b][c], w, acc);
            acch = fmaf(hgx[b][c], w, acch);
        }
        c1_out[b*DIM + f] = acc;
        h1gx[b][f] = fmaxf(acch, 0.f);
        __syncthreads();
        float acc2 = 0.f;                // b2 dropped (softmax-invariant)
        for (int c = 0; c < DIM; ++c) acc2 = fmaf(h1gx[b][c], g_w2[c*DIM + f], acc2);
        h2g_out[b*DIM + f] = acc2;
    }
}

// ---------------- pre3: kv_proj (512 blocks) || scatter (32 blocks).  544 x 256 ----------------
__global__ __launch_bounds__(256) void pre3_k(
    const float* __restrict__ points, const float* __restrict__ Wk1,
    const float* __restrict__ w_vs, const float* __restrict__ pe_b,
    const float* __restrict__ xyz, int* __restrict__ cursor,
    float* __restrict__ K1p, float* __restrict__ Vp,
    float2* __restrict__ sxy, int* __restrict__ sidx)
{
    __shared__ __align__(16) float pts[KVROWS*DIM];
    int t = threadIdx.x; int bx = blockIdx.x;
    if (bx < 512) {                      // kv_proj (round-7 exact math)
        int r0 = bx * KVROWS;
        #pragma unroll
        for (int k = 0; k < KVROWS*DIM/256; ++k) {
            int e = t + k*256;
            pts[e] = points[r0*DIM + e];
        }
        __syncthreads();
        int f = t & 127; int mat = t >> 7;
        const float* W = mat ? w_vs : Wk1;
        float* O = mat ? Vp : K1p;
        float addv = mat ? pe_b[f] : 0.f;
        float acc[KVROWS];
        #pragma unroll
        for (int r = 0; r < KVROWS; ++r) acc[r] = 0.f;
        const float4* pts4 = reinterpret_cast<const float4*>(pts);
        for (int c4 = 0; c4 < DIM/4; ++c4) {
            float w0 = W[(c4*4+0)*DIM + f];
            float w1 = W[(c4*4+1)*DIM + f];
            float w2 = W[(c4*4+2)*DIM + f];
            float w3 = W[(c4*4+3)*DIM + f];
            #pragma unroll
            for (int r = 0; r < KVROWS; ++r) {
                float4 p = pts4[r*(DIM/4) + c4];
                acc[r] = fmaf(p.x, w0, acc[r]);
                acc[r] = fmaf(p.y, w1, acc[r]);
                acc[r] = fmaf(p.z, w2, acc[r]);
                acc[r] = fmaf(p.w, w3, acc[r]);
            }
        }
        #pragma unroll
        for (int r = 0; r < KVROWS; ++r) O[(r0 + r)*DIM + f] = acc[r] + addv;
    } else {                             // scatter
        int gid = (bx - 512)*256 + t;
        int b = gid >> 12; int n = gid & (NPTS - 1);
        const float* p = xyz + (b*NPTS + n)*3;
        float x = p[0], y = p[1];
        int slot = atomicAdd(&cursor[b*NCELL + cell_of(y)*GRID + cell_of(x)], 1);
        sxy[b*NPTS + slot] = make_float2(x, y);
        sidx[b*NPTS + slot] = n;
    }
}

// ---------------- exact kNN: grid-binned candidates + 16x wave-argmin (unchanged) ----------------
__global__ __launch_bounds__(256) void knn_k(
    const float* __restrict__ xyz_q, const float2* __restrict__ sxy,
    const int* __restrict__ sidx, const int* __restrict__ cstart,
    int* __restrict__ knn_out)
{
    __shared__ float cand_d[4][CAP];
    __shared__ int   cand_i[4][CAP];
    int t = threadIdx.x; int wid = t >> 6, lane = t & 63;
    int bx = blockIdx.x; int b = bx >> 11; int q = (bx & 2047)*4 + wid;
    float xq = xyz_q[(b*NQ + q)*2 + 0];
    float yq = xyz_q[(b*NQ + q)*2 + 1];
    int cx = cell_of(xq), cy = cell_of(yq);
    const int* cs_b = cstart + b*(NCELL+1);
    float* cd = cand_d[wid]; int* ci = cand_i[wid];
    const float INF = 3.4e38f;
    const float CS = 1.0f/32.0f;
    int* outp = knn_out + (b*NQ + q)*KNN;
    int myIdx = 0;

    for (int R = 2; R < 9; ++R) {
        int x0 = max(cx-R, 0), x1 = min(cx+R, GRID-1);
        int y0 = max(cy-R, 0), y1 = min(cy+R, GRID-1);
        int cnt = 0;
        for (int ry = y0; ry <= y1; ++ry) {
            int s0 = cs_b[ry*GRID + x0];
            int e0 = cs_b[ry*GRID + x1 + 1];
            for (int o = s0 + lane; o < e0; o += 64) {
                float2 p = sxy[b*NPTS + o];
                float dx = __fadd_rn(xq, -p.x);
                float dy = __fadd_rn(yq, -p.y);
                float d = __fadd_rn(__fmul_rn(dx, dx), __fmul_rn(dy, dy));
                int slot = cnt + (o - s0);
                if (slot < CAP) { cd[slot] = d; ci[slot] = o; }
            }
            cnt += e0 - s0;
        }
        asm volatile("s_waitcnt lgkmcnt(0)" ::: "memory");
        __builtin_amdgcn_sched_barrier(0);

        float dr[6];
        #pragma unroll
        for (int k = 0; k < 6; ++k)
            dr[k] = (lane + k*64 < cnt) ? cd[lane + k*64] : INF;
        float d16 = INF;
        for (int r = 0; r < KNN; ++r) {
            float v = dr[0]; int s = lane;
            #pragma unroll
            for (int k = 1; k < 6; ++k)
                if (dr[k] < v) { v = dr[k]; s = lane + k*64; }
            #pragma unroll
            for (int off = 32; off >= 1; off >>= 1) {
                float ov = __shfl_xor(v, off);
                int   os = __shfl_xor(s, off);
                if (ov < v || (ov == v && os < s)) { v = ov; s = os; }
            }
            if (lane == r) myIdx = sidx[b*NPTS + ci[s]];
            if ((s & 63) == lane) {
                int k = s >> 6;
                if      (k == 0) dr[0] = INF;
                else if (k == 1) dr[1] = INF;
                else if (k == 2) dr[2] = INF;
                else if (k == 3) dr[3] = INF;
                else if (k == 4) dr[4] = INF;
                else             dr[5] = INF;
            }
            d16 = v;
        }
        float bl = (x0 > 0)      ? (xq - (float)x0*CS)       : INF;
        float br = (x1 < GRID-1) ? ((float)(x1+1)*CS - xq)   : INF;
        float bb = (y0 > 0)      ? (yq - (float)y0*CS)       : INF;
        float bt = (y1 < GRID-1) ? ((float)(y1+1)*CS - yq)   : INF;
        float safe = fminf(fminf(bl, br), fminf(bb, bt)) - 2e-6f;
        bool whole = (safe > 1e8f);
        bool ok = (cnt >= KNN) && (cnt <= CAP) && (whole || d16 <= safe*safe);
        if (ok || R == 8) {
            if (lane < KNN) outp[lane] = myIdx;
            break;
        }
    }
}

// ---------------- fused MFMA kernel (round-7 exact): 64 KB LDS, pwf from global ----------------
__global__ __launch_bounds__(512, 2) void fuse_k(
    const float* __restrict__ xyz_q, const float* __restrict__ xyz,
    const float* __restrict__ K1p, const float* __restrict__ Vp,
    const int* __restrict__ knn_idx,
    const float* __restrict__ c1_, const float* __restrict__ vg_,
    const float* __restrict__ h2g_, const float* __restrict__ pw32_,
    const ushort_t* __restrict__ pwf, const ushort_t* __restrict__ w2f,
    float* __restrict__ out)
{
    __shared__ __align__(16) ushort_t w2B[32*512];   // 32 KB
    __shared__ __align__(16) ushort_t h1b[8][2048];  // 32 KB (single bf16, per-wave)

    int t = threadIdx.x, lane = t & 63, wid = t >> 6;
    int bx = blockIdx.x; int b = bx >> 8; int qbase = (bx & 255) * 32;

    {   // stage w2 frags once per block (32 KB)
        const int4* s2 = (const int4*)w2f;  int4* d2 = (int4*)w2B;
        #pragma unroll
        for (int i = 0; i < 4; ++i) d2[t + i*512] = s2[t + i*512];
    }
    __syncthreads();

    int c16 = lane & 15, g = lane >> 4, rowbase = g*4;
    ushort_t* hb = h1b[wid];
    const vshort8* pwBv = (const vshort8*)pwf;       // global, L1-resident
    const vshort8* w2Bv = (const vshort8*)w2B;
    const vfloat4 vzero = (vfloat4){0.f, 0.f, 0.f, 0.f};

    // query-invariant hoists (per-lane): 40 regs
    float pw32r[16], c1r[8], hgr[8], vgr[8];
    #pragma unroll
    for (int n = 0; n < 16; ++n) pw32r[n] = pw32_[n*16 + c16];
    #pragma unroll
    for (int n = 0; n < 8; ++n) {
        c1r[n] = c1_[b*128 + n*16 + c16];
        hgr[n] = h2g_[b*128 + n*16 + c16];
        vgr[n] = vg_[b*128 + n*16 + c16];
    }

    #pragma unroll 1
    for (int qi = 0; qi < 4; ++qi) {
        int q = qbase + wid*4 + qi;
        float xq = xyz_q[(b*NQ + q)*2 + 0];
        float yq = xyz_q[(b*NQ + q)*2 + 1];
        int idxrow = knn_idx[(b*NQ + q)*KNN + c16];
        const float* p = xyz + (b*NPTS + idxrow)*3;
        float pd0 = xq - p[0], pd1 = yq - p[1], pd2 = p[2];
        int idxr[4];
        #pragma unroll
        for (int r = 0; r < 4; ++r) idxr[r] = __shfl(idxrow, rowbase + r);

        // emb A-fragment in registers: k = g*8 + j
        vshort8 eh;
        int k0 = g*8;
        #pragma unroll
        for (int j = 0; j < 8; ++j) {
            int k = k0 + j;
            float v;
            if (k < 3) {
                v = (k == 0) ? pd0 : (k == 1 ? pd1 : pd2);
            } else {
                int m = k - 3; int fi = m / 6; int rem = m - fi*6;
                int comp = (rem < 3) ? rem : rem - 3;
                float pdc = (comp == 0) ? pd0 : (comp == 1 ? pd1 : pd2);
                float fr = (fi == 0) ? 1.0f : (fi == 1) ? 8.75f : (fi == 2) ? 16.5f
                         : (fi == 3) ? 24.25f : 32.0f;
                float arg = pdc * fr;
                v = (rem < 3) ? __sinf(arg) : __cosf(arg);
            }
            eh[j] = (short)bf16_rne(v);
        }
        float c32 = __cosf(32.0f * pd2);
        float c32r[4];
        #pragma unroll
        for (int r = 0; r < 4; ++r) c32r[r] = __shfl(c32, rowbase + r);

        // K1p gather prefetch (transient: dies at end of pe1 phase)
        float k1v[4][8];
        #pragma unroll
        for (int r = 0; r < 4; ++r) {
            const float* kp = K1p + ((b*NPTS + idxr[r]) << 7) + c16;
            #pragma unroll
            for (int n = 0; n < 8; ++n) k1v[r][n] = kp[n*16];
        }

        // pe1 + h1 epilogue, one n at a time (acc1 live = 4 regs)
        #pragma unroll
        for (int n = 0; n < 8; ++n) {
            vfloat4 a = __builtin_amdgcn_mfma_f32_16x16x32_bf16(
                eh, pwBv[n*64 + lane], vzero, 0, 0, 0);
            int col = n*16 + c16;
            int s = col >> 5;
            int lp = ((col >> 3) & 3) << 4;
            int j = c16 & 7;
            #pragma unroll
            for (int r = 0; r < 4; ++r) {
                float h = c1r[n] - k1v[r][n] + fmaf(c32r[r], pw32r[n], a[r]);
                h = fmaxf(h, 0.f);
                hb[s*512 + (lp | (rowbase + r))*8 + j] = bf16_rne(h);
            }
        }
        asm volatile("s_waitcnt lgkmcnt(0)" ::: "memory");
        __builtin_amdgcn_sched_barrier(0);

        // GEMM2: [16x128]@[128x128], single bf16
        vfloat4 acc2[8];
        #pragma unroll
        for (int n = 0; n < 8; ++n) acc2[n] = vzero;
        #pragma unroll
        for (int s = 0; s < 4; ++s) {
            vshort8 ah = ((const vshort8*)hb)[s*64 + lane];
            #pragma unroll
            for (int n = 0; n < 8; ++n) {
                vshort8 bh = w2Bv[(n*4 + s)*64 + lane];
                acc2[n] = __builtin_amdgcn_mfma_f32_16x16x32_bf16(ah, bh, acc2[n], 0, 0, 0);
            }
        }

        // softmax over 17 slots, pe2 computed per-n, Vp gathers depth-1 pipelined
        const float* vbase[4];
        #pragma unroll
        for (int r = 0; r < 4; ++r) vbase[r] = Vp + ((b*NPTS + idxr[r]) << 7) + c16;
        float vvp[4];
        #pragma unroll
        for (int r = 0; r < 4; ++r) vvp[r] = vbase[r][0];

        #pragma unroll
        for (int n = 0; n < 8; ++n) {
            float vvc[4];
            #pragma unroll
            for (int r = 0; r < 4; ++r) vvc[r] = vvp[r];
            if (n < 7) {
                #pragma unroll
                for (int r = 0; r < 4; ++r) vvp[r] = vbase[r][(n+1)*16];
            }
            vfloat4 ap = __builtin_amdgcn_mfma_f32_16x16x32_bf16(
                eh, pwBv[(8 + n)*64 + lane], vzero, 0, 0, 0);
            #pragma unroll
            for (int r = 0; r < 4; ++r) ap[r] = fmaf(c32r[r], pw32r[8 + n], ap[r]);

            float hg = hgr[n];
            vfloat4 a2 = acc2[n];
            float mx = fmaxf(fmaxf(a2[0], a2[1]), fmaxf(a2[2], a2[3]));
            mx = fmaxf(mx, __shfl_xor(mx, 16));
            mx = fmaxf(mx, __shfl_xor(mx, 32));
            mx = fmaxf(mx, hg);
            float sum = 0.f, num = 0.f;
            #pragma unroll
            for (int r = 0; r < 4; ++r) {
                float ev = __expf(a2[r] - mx);
                float v = vvc[r] + ap[r];
                sum += ev;
                num = fmaf(ev, v, num);
            }
            sum += __shfl_xor(sum, 16); sum += __shfl_xor(sum, 32);
            num += __shfl_xor(num, 16); num += __shfl_xor(num, 32);
            float eg = __expf(hg - mx);
            sum += eg;
            num = fmaf(eg, vgr[n], num);
            if (g == 0) out[(b*NQ + q)*128 + n*16 + c16] = num / sum;
        }
        asm volatile("s_waitcnt lgkmcnt(0)" ::: "memory");
        __builtin_amdgcn_sched_barrier(0);
    }
}

extern "C" void kernel_launch(void* const* d_in, const int* in_sizes, int n_in,
                              void* d_out, int out_size, void* d_ws, size_t ws_size,
                              hipStream_t stream) {
    const float* xyz_q  = (const float*)d_in[0];
    const float* lat    = (const float*)d_in[1];
    const float* xyz    = (const float*)d_in[2];
    const float* points = (const float*)d_in[3];
    const float* w_qs   = (const float*)d_in[4];
    const float* w_ks   = (const float*)d_in[5];
    const float* w_vs   = (const float*)d_in[6];
    const float* w_kg   = (const float*)d_in[7];
    const float* w_vg   = (const float*)d_in[8];
    const float* g_w1   = (const float*)d_in[9];
    const float* g_b1   = (const float*)d_in[10];
    const float* g_w2   = (const float*)d_in[11];
    const float* g_b2   = (const float*)d_in[12];  // cancels under softmax
    const float* pe_w   = (const float*)d_in[13];
    const float* pe_b   = (const float*)d_in[14];
    float* out = (float*)d_out;
    (void)g_b2;

    float* ws   = (float*)d_ws;
    float* Vp   = ws;                          // 2*4096*128
    float* K1p  = Vp  + NB*NPTS*DIM;           // 2*4096*128
    float* Wk1  = K1p + NB*NPTS*DIM;           // 128*128
    float* pwc  = Wk1 + DIM*DIM;               // 64*256
    float* c1   = pwc + 64*256;                // 256
    float* vg   = c1  + NB*DIM;                // 256
    float* h2g  = vg  + NB*DIM;                // 256
    int*   knn  = (int*)(h2g + NB*DIM);        // 2*8192*16
    ushort_t* pwf = (ushort_t*)(knn + NB*NQ*KNN);   // 16 KB
    ushort_t* w2f = pwf + 16*64*8;                  // 32 KB
    int* cellcnt  = (int*)(w2f + 32*64*8);          // 2*1024
    int* cellstart = cellcnt + NB*NCELL;            // 2*1025
    int* cursor    = cellstart + NB*(NCELL+1);      // 2*1024
    int* sidx      = cursor + NB*NCELL;             // 2*4096
    float2* sxy    = (float2*)(sidx + NB*NPTS);     // 2*4096 float2

    hipMemsetAsync(cellcnt, 0, NB*NCELL*sizeof(int), stream);
    pre1_k<<<160, 256, 0, stream>>>(w_ks, g_w1, pe_w, xyz, Wk1, pwc, cellcnt);
    pre2_k<<<15, 256, 0, stream>>>(pwc, g_w2, cellcnt,
                                   lat, w_qs, w_kg, w_vg, g_w1, g_b1, pe_b,
                                   pwf, w2f, cellstart, cursor, c1, vg, h2g);
    pre3_k<<<544, 256, 0, stream>>>(points, Wk1, w_vs, pe_b, xyz, cursor,
                                    K1p, Vp, sxy, sidx);
    knn_k<<<NB*NQ/4, 256, 0, stream>>>(xyz_q, sxy, sidx, cellstart, knn);
    fuse_k<<<NB*NQ/32, 512, 0, stream>>>(xyz_q, xyz, K1p, Vp, knn, c1, vg, h2g,
                                         pwc + 32*256, pwf, w2f, out);
}

// Round 13
// 136.182 us; speedup vs baseline: 1.4372x; 1.0403x over previous
//
#include <hip/hip_runtime.h>
#include <cstdint>

#define DIM   128
#define KNN   16
#define NB    2
#define NQ    8192
#define NPTS  4096
#define KVROWS 16
#define GRID  32
#define NCELL (GRID*GRID)
#define CAP   384

typedef unsigned short ushort_t;
typedef short vshort8 __attribute__((ext_vector_type(8)));
typedef float vfloat4 __attribute__((ext_vector_type(4)));

__device__ __forceinline__ ushort_t bf16_rne(float f) {
    unsigned u = __float_as_uint(f);
    unsigned r = u + 0x7FFFu + ((u >> 16) & 1u);
    return (ushort_t)(r >> 16);
}
__device__ __forceinline__ int cell_of(float x) {
    int c = (int)(x * 32.0f);
    return min(max(c, 0), GRID - 1);
}

// pack f32 [K][ncols] -> MFMA B-fragments (single bf16), device body
__device__ __forceinline__ void pack_body(
    const float* __restrict__ src, int K, int ncols, int NT, int KS,
    ushort_t* __restrict__ dst, int gid)
{
    int total = NT*KS*64;
    if (gid >= total) return;
    int lane = gid & 63; int c = gid >> 6;
    int s = c % KS; int n = c / KS;
    int k0 = s*32 + ((lane >> 4) << 3);
    int col = n*16 + (lane & 15);
    vshort8 v;
    #pragma unroll
    for (int i = 0; i < 8; ++i) {
        int k = k0 + i;
        float f = (k < K) ? src[k*ncols + col] : 0.f;
        v[i] = (short)bf16_rne(f);
    }
    *(vshort8*)(dst + gid*8) = v;
}

// shared 256-thread exclusive prefix over 1024 cells (4/thread)
__device__ __forceinline__ void scan1024(
    const int* __restrict__ cnt, int* __restrict__ cs, int* __restrict__ cu,
    int* __restrict__ ss, int t)
{
    int v0 = cnt[t*4 + 0];
    int v1 = cnt[t*4 + 1];
    int v2 = cnt[t*4 + 2];
    int v3 = cnt[t*4 + 3];
    int p0 = v0, p1 = p0 + v1, p2 = p1 + v2, p3 = p2 + v3;
    ss[t] = p3;
    __syncthreads();
    for (int off = 1; off < 256; off <<= 1) {
        int add = (t >= off) ? ss[t - off] : 0;
        __syncthreads();
        ss[t] += add;
        __syncthreads();
    }
    int excl = ss[t] - p3;
    cs[t*4 + 0] = excl;        cu[t*4 + 0] = excl;
    cs[t*4 + 1] = excl + p0;   cu[t*4 + 1] = excl + p0;
    cs[t*4 + 2] = excl + p1;   cu[t*4 + 2] = excl + p1;
    cs[t*4 + 3] = excl + p2;   cu[t*4 + 3] = excl + p2;
    if (t == 255) cs[NCELL] = ss[255];
}

// ---------------- pre1: wprod || point-cellcount || query-cellcount.  224 x 256 ----------------
__global__ __launch_bounds__(256) void pre1_k(
    const float* __restrict__ w_ks, const float* __restrict__ g_w1,
    const float* __restrict__ pe_w, const float* __restrict__ xyz,
    const float* __restrict__ xyz_q,
    float* __restrict__ Wk1, float* __restrict__ pwc,
    int* __restrict__ cellcnt, int* __restrict__ qcnt)
{
    int t = threadIdx.x; int bx = blockIdx.x;
    if (bx < 64) {                       // Wk1
        int row = bx*2 + (t >> 7); int f = t & 127;
        float acc = 0.f;
        for (int c = 0; c < 128; ++c) acc = fmaf(w_ks[row*128 + c], g_w1[c*128 + f], acc);
        Wk1[row*128 + f] = acc;
    } else if (bx < 128) {               // pwc
        int r = bx - 64; int col = t;
        float v = 0.f;
        if (r < 33) {
            if (col < 128) {
                float a = 0.f;
                for (int c = 0; c < 128; ++c) a = fmaf(pe_w[r*128 + c], g_w1[c*128 + col], a);
                v = a;
            } else {
                v = pe_w[r*128 + (col - 128)];
            }
        }
        pwc[r*256 + col] = v;
    } else if (bx < 160) {               // point cellcount
        int gid = (bx - 128)*256 + t;
        int b = gid >> 12; int n = gid & (NPTS - 1);
        const float* p = xyz + (b*NPTS + n)*3;
        atomicAdd(&cellcnt[b*NCELL + cell_of(p[1])*GRID + cell_of(p[0])], 1);
    } else {                             // query cellcount (64 blocks)
        int gid = (bx - 160)*256 + t;
        int b = gid >> 13; int q = gid & (NQ - 1);
        const float* p = xyz_q + (b*NQ + q)*2;
        atomicAdd(&qcnt[b*NCELL + cell_of(p[1])*GRID + cell_of(p[0])], 1);
    }
}

// ---------------- pre2: packs || point-scan || query-scan || prep_global.  17 x 256 ----------------
__global__ __launch_bounds__(256) void pre2_k(
    const float* __restrict__ pwc, const float* __restrict__ g_w2,
    const int* __restrict__ cnt, const int* __restrict__ qcnt,
    const float* __restrict__ lat, const float* __restrict__ w_qs,
    const float* __restrict__ w_kg, const float* __restrict__ w_vg,
    const float* __restrict__ g_w1, const float* __restrict__ g_b1,
    const float* __restrict__ pe_b,
    ushort_t* __restrict__ pwf, ushort_t* __restrict__ w2f,
    int* __restrict__ cell_start, int* __restrict__ cursor,
    int* __restrict__ qstart, int* __restrict__ qcursor,
    float* __restrict__ c1_out, float* __restrict__ vg_out, float* __restrict__ h2g_out)
{
    __shared__ int ss[256];
    __shared__ float qs[NB][DIM];
    __shared__ float hgx[NB][DIM];
    __shared__ float h1gx[NB][DIM];
    int t = threadIdx.x; int bx = blockIdx.x;
    if (bx < 4) {
        pack_body(pwc, 32, 256, 16, 1, pwf, bx*256 + t);
    } else if (bx < 12) {
        pack_body(g_w2, 128, 128, 8, 4, w2f, (bx - 4)*256 + t);
    } else if (bx < 14) {                // point prefix, batch b
        int b = bx - 12;
        scan1024(cnt + b*NCELL, cell_start + b*(NCELL+1), cursor + b*NCELL, ss, t);
    } else if (bx < 16) {                // query prefix, batch b
        int b = bx - 14;
        scan1024(qcnt + b*NCELL, qstart + b*(NCELL+1), qcursor + b*NCELL, ss, t);
    } else {                             // prep_global
        int b = t >> 7; int f = t & 127;
        float aq = 0.f, ak = 0.f, av = 0.f;
        for (int c = 0; c < DIM; ++c) {
            float l = lat[b*DIM + c];
            aq = fmaf(l, w_qs[c*DIM + f], aq);
            ak = fmaf(l, w_kg[c*DIM + f], ak);
            av = fmaf(l, w_vg[c*DIM + f], av);
        }
        vg_out[b*DIM + f] = av;
        qs[b][f] = aq + pe_b[f];
        hgx[b][f] = aq - ak;
        __syncthreads();
        float acc = g_b1[f], acch = g_b1[f];
        for (int c = 0; c < DIM; ++c) {
            float w = g_w1[c*DIM + f];
            acc  = fmaf(qs[b][c], w, acc);
            acch = fmaf(hgx[b][c], w, acch);
        }
        c1_out[b*DIM + f] = acc;
        h1gx[b][f] = fmaxf(acch, 0.f);
        __syncthreads();
        float acc2 = 0.f;                // b2 dropped (softmax-invariant)
        for (int c = 0; c < DIM; ++c) acc2 = fmaf(h1gx[b][c], g_w2[c*DIM + f], acc2);
        h2g_out[b*DIM + f] = acc2;
    }
}

// ---------------- pre3: kv_proj || point-scatter || query-scatter.  608 x 256 ----------------
__global__ __launch_bounds__(256) void pre3_k(
    const float* __restrict__ points, const float* __restrict__ Wk1,
    const float* __restrict__ w_vs, const float* __restrict__ pe_b,
    const float* __restrict__ xyz, const float* __restrict__ xyz_q,
    int* __restrict__ cursor, int* __restrict__ qcursor,
    float* __restrict__ K1p, float* __restrict__ Vp,
    float2* __restrict__ sxy, int* __restrict__ sidx,
    float2* __restrict__ qsxy, int* __restrict__ qsidx)
{
    __shared__ __align__(16) float pts[KVROWS*DIM];
    int t = threadIdx.x; int bx = blockIdx.x;
    if (bx < 512) {                      // kv_proj (round-7 exact math)
        int r0 = bx * KVROWS;
        #pragma unroll
        for (int k = 0; k < KVROWS*DIM/256; ++k) {
            int e = t + k*256;
            pts[e] = points[r0*DIM + e];
        }
        __syncthreads();
        int f = t & 127; int mat = t >> 7;
        const float* W = mat ? w_vs : Wk1;
        float* O = mat ? Vp : K1p;
        float addv = mat ? pe_b[f] : 0.f;
        float acc[KVROWS];
        #pragma unroll
        for (int r = 0; r < KVROWS; ++r) acc[r] = 0.f;
        const float4* pts4 = reinterpret_cast<const float4*>(pts);
        for (int c4 = 0; c4 < DIM/4; ++c4) {
            float w0 = W[(c4*4+0)*DIM + f];
            float w1 = W[(c4*4+1)*DIM + f];
            float w2 = W[(c4*4+2)*DIM + f];
            float w3 = W[(c4*4+3)*DIM + f];
            #pragma unroll
            for (int r = 0; r < KVROWS; ++r) {
                float4 p = pts4[r*(DIM/4) + c4];
                acc[r] = fmaf(p.x, w0, acc[r]);
                acc[r] = fmaf(p.y, w1, acc[r]);
                acc[r] = fmaf(p.z, w2, acc[r]);
                acc[r] = fmaf(p.w, w3, acc[r]);
            }
        }
        #pragma unroll
        for (int r = 0; r < KVROWS; ++r) O[(r0 + r)*DIM + f] = acc[r] + addv;
    } else if (bx < 544) {               // point scatter
        int gid = (bx - 512)*256 + t;
        int b = gid >> 12; int n = gid & (NPTS - 1);
        const float* p = xyz + (b*NPTS + n)*3;
        float x = p[0], y = p[1];
        int slot = atomicAdd(&cursor[b*NCELL + cell_of(y)*GRID + cell_of(x)], 1);
        sxy[b*NPTS + slot] = make_float2(x, y);
        sidx[b*NPTS + slot] = n;
    } else {                             // query scatter (64 blocks)
        int gid = (bx - 544)*256 + t;
        int b = gid >> 13; int q = gid & (NQ - 1);
        const float* p = xyz_q + (b*NQ + q)*2;
        float x = p[0], y = p[1];
        int slot = atomicAdd(&qcursor[b*NCELL + cell_of(y)*GRID + cell_of(x)], 1);
        qsxy[b*NQ + slot] = make_float2(x, y);
        qsidx[b*NQ + slot] = q;
    }
}

// ---------------- exact kNN over SORTED queries ----------------
__global__ __launch_bounds__(256) void knn_k(
    const float2* __restrict__ qsxy, const float2* __restrict__ sxy,
    const int* __restrict__ sidx, const int* __restrict__ cstart,
    int* __restrict__ knn_out)
{
    __shared__ float cand_d[4][CAP];
    __shared__ int   cand_i[4][CAP];
    int t = threadIdx.x; int wid = t >> 6, lane = t & 63;
    int bx = blockIdx.x; int b = bx >> 11; int q = (bx & 2047)*4 + wid;
    float2 qp = qsxy[b*NQ + q];
    float xq = qp.x, yq = qp.y;
    int cx = cell_of(xq), cy = cell_of(yq);
    const int* cs_b = cstart + b*(NCELL+1);
    float* cd = cand_d[wid]; int* ci = cand_i[wid];
    const float INF = 3.4e38f;
    const float CS = 1.0f/32.0f;
    int* outp = knn_out + (b*NQ + q)*KNN;
    int myIdx = 0;

    for (int R = 2; R < 9; ++R) {
        int x0 = max(cx-R, 0), x1 = min(cx+R, GRID-1);
        int y0 = max(cy-R, 0), y1 = min(cy+R, GRID-1);
        int cnt = 0;
        for (int ry = y0; ry <= y1; ++ry) {
            int s0 = cs_b[ry*GRID + x0];
            int e0 = cs_b[ry*GRID + x1 + 1];
            for (int o = s0 + lane; o < e0; o += 64) {
                float2 p = sxy[b*NPTS + o];
                float dx = __fadd_rn(xq, -p.x);
                float dy = __fadd_rn(yq, -p.y);
                float d = __fadd_rn(__fmul_rn(dx, dx), __fmul_rn(dy, dy));
                int slot = cnt + (o - s0);
                if (slot < CAP) { cd[slot] = d; ci[slot] = o; }
            }
            cnt += e0 - s0;
        }
        asm volatile("s_waitcnt lgkmcnt(0)" ::: "memory");
        __builtin_amdgcn_sched_barrier(0);

        float dr[6];
        #pragma unroll
        for (int k = 0; k < 6; ++k)
            dr[k] = (lane + k*64 < cnt) ? cd[lane + k*64] : INF;
        float d16 = INF;
        for (int r = 0; r < KNN; ++r) {
            float v = dr[0]; int s = lane;
            #pragma unroll
            for (int k = 1; k < 6; ++k)
                if (dr[k] < v) { v = dr[k]; s = lane + k*64; }
            #pragma unroll
            for (int off = 32; off >= 1; off >>= 1) {
                float ov = __shfl_xor(v, off);
                int   os = __shfl_xor(s, off);
                if (ov < v || (ov == v && os < s)) { v = ov; s = os; }
            }
            if (lane == r) myIdx = sidx[b*NPTS + ci[s]];
            if ((s & 63) == lane) {
                int k = s >> 6;
                if      (k == 0) dr[0] = INF;
                else if (k == 1) dr[1] = INF;
                else if (k == 2) dr[2] = INF;
                else if (k == 3) dr[3] = INF;
                else if (k == 4) dr[4] = INF;
                else             dr[5] = INF;
            }
            d16 = v;
        }
        float bl = (x0 > 0)      ? (xq - (float)x0*CS)       : INF;
        float br = (x1 < GRID-1) ? ((float)(x1+1)*CS - xq)   : INF;
        float bb = (y0 > 0)      ? (yq - (float)y0*CS)       : INF;
        float bt = (y1 < GRID-1) ? ((float)(y1+1)*CS - yq)   : INF;
        float safe = fminf(fminf(bl, br), fminf(bb, bt)) - 2e-6f;
        bool whole = (safe > 1e8f);
        bool ok = (cnt >= KNN) && (cnt <= CAP) && (whole || d16 <= safe*safe);
        if (ok || R == 8) {
            if (lane < KNN) outp[lane] = myIdx;
            break;
        }
    }
}

// ---------------- fused MFMA kernel (round-7 core) over SORTED queries + XCD swizzle ----------------
__global__ __launch_bounds__(512, 2) void fuse_k(
    const float2* __restrict__ qsxy, const int* __restrict__ qsidx,
    const float* __restrict__ xyz,
    const float* __restrict__ K1p, const float* __restrict__ Vp,
    const int* __restrict__ knn_idx,
    const float* __restrict__ c1_, const float* __restrict__ vg_,
    const float* __restrict__ h2g_, const float* __restrict__ pw32_,
    const ushort_t* __restrict__ pwf, const ushort_t* __restrict__ w2f,
    float* __restrict__ out)
{
    __shared__ __align__(16) ushort_t w2B[32*512];   // 32 KB
    __shared__ __align__(16) ushort_t h1b[8][2048];  // 32 KB (single bf16, per-wave)

    int t = threadIdx.x, lane = t & 63, wid = t >> 6;
    // bijective XCD swizzle over 512 blocks: each XCD gets a contiguous
    // 64-block (2048 sorted-query) spatial slice -> K1p/Vp slice fits its L2.
    int sid = (blockIdx.x & 7) * 64 + (blockIdx.x >> 3);
    int b = sid >> 8; int qbase = (sid & 255) * 32;

    {   // stage w2 frags once per block (32 KB)
        const int4* s2 = (const int4*)w2f;  int4* d2 = (int4*)w2B;
        #pragma unroll
        for (int i = 0; i < 4; ++i) d2[t + i*512] = s2[t + i*512];
    }
    __syncthreads();

    int c16 = lane & 15, g = lane >> 4, rowbase = g*4;
    ushort_t* hb = h1b[wid];
    const vshort8* pwBv = (const vshort8*)pwf;       // global, L1-resident
    const vshort8* w2Bv = (const vshort8*)w2B;
    const vfloat4 vzero = (vfloat4){0.f, 0.f, 0.f, 0.f};

    // query-invariant hoists (per-lane): 40 regs
    float pw32r[16], c1r[8], hgr[8], vgr[8];
    #pragma unroll
    for (int n = 0; n < 16; ++n) pw32r[n] = pw32_[n*16 + c16];
    #pragma unroll
    for (int n = 0; n < 8; ++n) {
        c1r[n] = c1_[b*128 + n*16 + c16];
        hgr[n] = h2g_[b*128 + n*16 + c16];
        vgr[n] = vg_[b*128 + n*16 + c16];
    }

    #pragma unroll 1
    for (int qi = 0; qi < 4; ++qi) {
        int q = qbase + wid*4 + qi;                  // sorted index
        float2 qp = qsxy[b*NQ + q];
        float xq = qp.x, yq = qp.y;
        int qorig = qsidx[b*NQ + q];
        int idxrow = knn_idx[(b*NQ + q)*KNN + c16];
        const float* p = xyz + (b*NPTS + idxrow)*3;
        float pd0 = xq - p[0], pd1 = yq - p[1], pd2 = p[2];
        int idxr[4];
        #pragma unroll
        for (int r = 0; r < 4; ++r) idxr[r] = __shfl(idxrow, rowbase + r);

        // emb A-fragment in registers: k = g*8 + j
        vshort8 eh;
        int k0 = g*8;
        #pragma unroll
        for (int j = 0; j < 8; ++j) {
            int k = k0 + j;
            float v;
            if (k < 3) {
                v = (k == 0) ? pd0 : (k == 1 ? pd1 : pd2);
            } else {
                int m = k - 3; int fi = m / 6; int rem = m - fi*6;
                int comp = (rem < 3) ? rem : rem - 3;
                float pdc = (comp == 0) ? pd0 : (comp == 1 ? pd1 : pd2);
                float fr = (fi == 0) ? 1.0f : (fi == 1) ? 8.75f : (fi == 2) ? 16.5f
                         : (fi == 3) ? 24.25f : 32.0f;
                float arg = pdc * fr;
                v = (rem < 3) ? __sinf(arg) : __cosf(arg);
            }
            eh[j] = (short)bf16_rne(v);
        }
        float c32 = __cosf(32.0f * pd2);
        float c32r[4];
        #pragma unroll
        for (int r = 0; r < 4; ++r) c32r[r] = __shfl(c32, rowbase + r);

        // K1p gather prefetch (transient: dies at end of pe1 phase)
        float k1v[4][8];
        #pragma unroll
        for (int r = 0; r < 4; ++r) {
            const float* kp = K1p + ((b*NPTS + idxr[r]) << 7) + c16;
            #pragma unroll
            for (int n = 0; n < 8; ++n) k1v[r][n] = kp[n*16];
        }

        // pe1 + h1 epilogue, one n at a time (acc1 live = 4 regs)
        #pragma unroll
        for (int n = 0; n < 8; ++n) {
            vfloat4 a = __builtin_amdgcn_mfma_f32_16x16x32_bf16(
                eh, pwBv[n*64 + lane], vzero, 0, 0, 0);
            int col = n*16 + c16;
            int s = col >> 5;
            int lp = ((col >> 3) & 3) << 4;
            int j = c16 & 7;
            #pragma unroll
            for (int r = 0; r < 4; ++r) {
                float h = c1r[n] - k1v[r][n] + fmaf(c32r[r], pw32r[n], a[r]);
                h = fmaxf(h, 0.f);
                hb[s*512 + (lp | (rowbase + r))*8 + j] = bf16_rne(h);
            }
        }
        asm volatile("s_waitcnt lgkmcnt(0)" ::: "memory");
        __builtin_amdgcn_sched_barrier(0);

        // GEMM2: [16x128]@[128x128], single bf16
        vfloat4 acc2[8];
        #pragma unroll
        for (int n = 0; n < 8; ++n) acc2[n] = vzero;
        #pragma unroll
        for (int s = 0; s < 4; ++s) {
            vshort8 ah = ((const vshort8*)hb)[s*64 + lane];
            #pragma unroll
            for (int n = 0; n < 8; ++n) {
                vshort8 bh = w2Bv[(n*4 + s)*64 + lane];
                acc2[n] = __builtin_amdgcn_mfma_f32_16x16x32_bf16(ah, bh, acc2[n], 0, 0, 0);
            }
        }

        // softmax over 17 slots, pe2 computed per-n, Vp gathers depth-1 pipelined
        const float* vbase[4];
        #pragma unroll
        for (int r = 0; r < 4; ++r) vbase[r] = Vp + ((b*NPTS + idxr[r]) << 7) + c16;
        float vvp[4];
        #pragma unroll
        for (int r = 0; r < 4; ++r) vvp[r] = vbase[r][0];

        #pragma unroll
        for (int n = 0; n < 8; ++n) {
            float vvc[4];
            #pragma unroll
            for (int r = 0; r < 4; ++r) vvc[r] = vvp[r];
            if (n < 7) {
                #pragma unroll
                for (int r = 0; r < 4; ++r) vvp[r] = vbase[r][(n+1)*16];
            }
            vfloat4 ap = __builtin_amdgcn_mfma_f32_16x16x32_bf16(
                eh, pwBv[(8 + n)*64 + lane], vzero, 0, 0, 0);
            #pragma unroll
            for (int r = 0; r < 4; ++r) ap[r] = fmaf(c32r[r], pw32r[8 + n], ap[r]);

            float hg = hgr[n];
            vfloat4 a2 = acc2[n];
            float mx = fmaxf(fmaxf(a2[0], a2[1]), fmaxf(a2[2], a2[3]));
            mx = fmaxf(mx, __shfl_xor(mx, 16));
            mx = fmaxf(mx, __shfl_xor(mx, 32));
            mx = fmaxf(mx, hg);
            float sum = 0.f, num = 0.f;
            #pragma unroll
            for (int r = 0; r < 4; ++r) {
                float ev = __expf(a2[r] - mx);
                float v = vvc[r] + ap[r];
                sum += ev;
                num = fmaf(ev, v, num);
            }
            sum += __shfl_xor(sum, 16); sum += __shfl_xor(sum, 32);
            num += __shfl_xor(num, 16); num += __shfl_xor(num, 32);
            float eg = __expf(hg - mx);
            sum += eg;
            num = fmaf(eg, vgr[n], num);
            if (g == 0) out[(b*NQ + qorig)*128 + n*16 + c16] = num / sum;
        }
        asm volatile("s_waitcnt lgkmcnt(0)" ::: "memory");
        __builtin_amdgcn_sched_barrier(0);
    }
}

extern "C" void kernel_launch(void* const* d_in, const int* in_sizes, int n_in,
                              void* d_out, int out_size, void* d_ws, size_t ws_size,
                              hipStream_t stream) {
    const float* xyz_q  = (const float*)d_in[0];
    const float* lat    = (const float*)d_in[1];
    const float* xyz    = (const float*)d_in[2];
    const float* points = (const float*)d_in[3];
    const float* w_qs   = (const float*)d_in[4];
    const float* w_ks   = (const float*)d_in[5];
    const float* w_vs   = (const float*)d_in[6];
    const float* w_kg   = (const float*)d_in[7];
    const float* w_vg   = (const float*)d_in[8];
    const float* g_w1   = (const float*)d_in[9];
    const float* g_b1   = (const float*)d_in[10];
    const float* g_w2   = (const float*)d_in[11];
    const float* g_b2   = (const float*)d_in[12];  // cancels under softmax
    const float* pe_w   = (const float*)d_in[13];
    const float* pe_b   = (const float*)d_in[14];
    float* out = (float*)d_out;
    (void)g_b2;

    float* ws   = (float*)d_ws;
    float* Vp   = ws;                          // 2*4096*128
    float* K1p  = Vp  + NB*NPTS*DIM;           // 2*4096*128
    float* Wk1  = K1p + NB*NPTS*DIM;           // 128*128
    float* pwc  = Wk1 + DIM*DIM;               // 64*256
    float* c1   = pwc + 64*256;                // 256
    float* vg   = c1  + NB*DIM;                // 256
    float* h2g  = vg  + NB*DIM;                // 256
    int*   knn  = (int*)(h2g + NB*DIM);        // 2*8192*16
    ushort_t* pwf = (ushort_t*)(knn + NB*NQ*KNN);   // 16 KB
    ushort_t* w2f = pwf + 16*64*8;                  // 32 KB
    int* cellcnt  = (int*)(w2f + 32*64*8);          // 2*1024   (zeroed)
    int* qcnt     = cellcnt + NB*NCELL;             // 2*1024   (zeroed, adjacent)
    int* cellstart = qcnt + NB*NCELL;               // 2*1025
    int* cursor    = cellstart + NB*(NCELL+1);      // 2*1024
    int* qstart    = cursor + NB*NCELL;             // 2*1025
    int* qcursor   = qstart + NB*(NCELL+1);         // 2*1024
    int* sidx      = qcursor + NB*NCELL;            // 2*4096
    float2* sxy    = (float2*)(sidx + NB*NPTS);     // 2*4096 float2
    int* qsidx     = (int*)(sxy + NB*NPTS);         // 2*8192
    float2* qsxy   = (float2*)(qsidx + NB*NQ);      // 2*8192 float2

    hipMemsetAsync(cellcnt, 0, 2*NB*NCELL*sizeof(int), stream);  // cellcnt + qcnt
    pre1_k<<<224, 256, 0, stream>>>(w_ks, g_w1, pe_w, xyz, xyz_q,
                                    Wk1, pwc, cellcnt, qcnt);
    pre2_k<<<17, 256, 0, stream>>>(pwc, g_w2, cellcnt, qcnt,
                                   lat, w_qs, w_kg, w_vg, g_w1, g_b1, pe_b,
                                   pwf, w2f, cellstart, cursor, qstart, qcursor,
                                   c1, vg, h2g);
    pre3_k<<<608, 256, 0, stream>>>(points, Wk1, w_vs, pe_b, xyz, xyz_q,
                                    cursor, qcursor, K1p, Vp, sxy, sidx, qsxy, qsidx);
    knn_k<<<NB*NQ/4, 256, 0, stream>>>(qsxy, sxy, sidx, cellstart, knn);
    fuse_k<<<NB*NQ/32, 512, 0, stream>>>(qsxy, qsidx, xyz, K1p, Vp, knn, c1, vg, h2g,
                                         pwc + 32*256, pwf, w2f, out);
}

// Round 14
// 109.709 us; speedup vs baseline: 1.7840x; 1.2413x over previous
//
#include <hip/hip_runtime.h>
#include <cstdint>

#define DIM   128
#define KNN   16
#define NB    2
#define NQ    8192
#define NPTS  4096
#define KVROWS 16
#define GRID  32
#define NCELL (GRID*GRID)
#define CAP   384

typedef unsigned short ushort_t;
typedef short vshort8 __attribute__((ext_vector_type(8)));
typedef float vfloat4 __attribute__((ext_vector_type(4)));

__device__ __forceinline__ ushort_t bf16_rne(float f) {
    unsigned u = __float_as_uint(f);
    unsigned r = u + 0x7FFFu + ((u >> 16) & 1u);
    return (ushort_t)(r >> 16);
}
__device__ __forceinline__ int cell_of(float x) {
    int c = (int)(x * 32.0f);
    return min(max(c, 0), GRID - 1);
}

// pack f32 [K][ncols] -> MFMA B-fragments (single bf16), device body
__device__ __forceinline__ void pack_body(
    const float* __restrict__ src, int K, int ncols, int NT, int KS,
    ushort_t* __restrict__ dst, int gid)
{
    int total = NT*KS*64;
    if (gid >= total) return;
    int lane = gid & 63; int c = gid >> 6;
    int s = c % KS; int n = c / KS;
    int k0 = s*32 + ((lane >> 4) << 3);
    int col = n*16 + (lane & 15);
    vshort8 v;
    #pragma unroll
    for (int i = 0; i < 8; ++i) {
        int k = k0 + i;
        float f = (k < K) ? src[k*ncols + col] : 0.f;
        v[i] = (short)bf16_rne(f);
    }
    *(vshort8*)(dst + gid*8) = v;
}

// shared 256-thread exclusive prefix over 1024 cells (4/thread)
__device__ __forceinline__ void scan1024(
    const int* __restrict__ cnt, int* __restrict__ cs, int* __restrict__ cu,
    int* __restrict__ ss, int t)
{
    int v0 = cnt[t*4 + 0];
    int v1 = cnt[t*4 + 1];
    int v2 = cnt[t*4 + 2];
    int v3 = cnt[t*4 + 3];
    int p0 = v0, p1 = p0 + v1, p2 = p1 + v2, p3 = p2 + v3;
    ss[t] = p3;
    __syncthreads();
    for (int off = 1; off < 256; off <<= 1) {
        int add = (t >= off) ? ss[t - off] : 0;
        __syncthreads();
        ss[t] += add;
        __syncthreads();
    }
    int excl = ss[t] - p3;
    cs[t*4 + 0] = excl;        cu[t*4 + 0] = excl;
    cs[t*4 + 1] = excl + p0;   cu[t*4 + 1] = excl + p0;
    cs[t*4 + 2] = excl + p1;   cu[t*4 + 2] = excl + p1;
    cs[t*4 + 3] = excl + p2;   cu[t*4 + 3] = excl + p2;
    if (t == 255) cs[NCELL] = ss[255];
}

// ---------------- pre1: wprod || point-cellcount || query-cellcount.  224 x 256 ----------------
__global__ __launch_bounds__(256) void pre1_k(
    const float* __restrict__ w_ks, const float* __restrict__ g_w1,
    const float* __restrict__ pe_w, const float* __restrict__ xyz,
    const float* __restrict__ xyz_q,
    float* __restrict__ Wk1, float* __restrict__ pwc,
    int* __restrict__ cellcnt, int* __restrict__ qcnt)
{
    int t = threadIdx.x; int bx = blockIdx.x;
    if (bx < 64) {                       // Wk1
        int row = bx*2 + (t >> 7); int f = t & 127;
        float acc = 0.f;
        for (int c = 0; c < 128; ++c) acc = fmaf(w_ks[row*128 + c], g_w1[c*128 + f], acc);
        Wk1[row*128 + f] = acc;
    } else if (bx < 128) {               // pwc
        int r = bx - 64; int col = t;
        float v = 0.f;
        if (r < 33) {
            if (col < 128) {
                float a = 0.f;
                for (int c = 0; c < 128; ++c) a = fmaf(pe_w[r*128 + c], g_w1[c*128 + col], a);
                v = a;
            } else {
                v = pe_w[r*128 + (col - 128)];
            }
        }
        pwc[r*256 + col] = v;
    } else if (bx < 160) {               // point cellcount
        int gid = (bx - 128)*256 + t;
        int b = gid >> 12; int n = gid & (NPTS - 1);
        const float* p = xyz + (b*NPTS + n)*3;
        atomicAdd(&cellcnt[b*NCELL + cell_of(p[1])*GRID + cell_of(p[0])], 1);
    } else {                             // query cellcount (64 blocks)
        int gid = (bx - 160)*256 + t;
        int b = gid >> 13; int q = gid & (NQ - 1);
        const float* p = xyz_q + (b*NQ + q)*2;
        atomicAdd(&qcnt[b*NCELL + cell_of(p[1])*GRID + cell_of(p[0])], 1);
    }
}

// ---------------- pre2: packs || point-scan || query-scan || prep_global.  17 x 256 ----------------
__global__ __launch_bounds__(256) void pre2_k(
    const float* __restrict__ pwc, const float* __restrict__ g_w2,
    const int* __restrict__ cnt, const int* __restrict__ qcnt,
    const float* __restrict__ lat, const float* __restrict__ w_qs,
    const float* __restrict__ w_kg, const float* __restrict__ w_vg,
    const float* __restrict__ g_w1, const float* __restrict__ g_b1,
    const float* __restrict__ pe_b,
    ushort_t* __restrict__ pwf, ushort_t* __restrict__ w2f,
    int* __restrict__ cell_start, int* __restrict__ cursor,
    int* __restrict__ qstart, int* __restrict__ qcursor,
    float* __restrict__ c1_out, float* __restrict__ vg_out, float* __restrict__ h2g_out)
{
    __shared__ int ss[256];
    __shared__ float qs[NB][DIM];
    __shared__ float hgx[NB][DIM];
    __shared__ float h1gx[NB][DIM];
    int t = threadIdx.x; int bx = blockIdx.x;
    if (bx < 4) {
        pack_body(pwc, 32, 256, 16, 1, pwf, bx*256 + t);
    } else if (bx < 12) {
        pack_body(g_w2, 128, 128, 8, 4, w2f, (bx - 4)*256 + t);
    } else if (bx < 14) {                // point prefix, batch b
        int b = bx - 12;
        scan1024(cnt + b*NCELL, cell_start + b*(NCELL+1), cursor + b*NCELL, ss, t);
    } else if (bx < 16) {                // query prefix, batch b
        int b = bx - 14;
        scan1024(qcnt + b*NCELL, qstart + b*(NCELL+1), qcursor + b*NCELL, ss, t);
    } else {                             // prep_global
        int b = t >> 7; int f = t & 127;
        float aq = 0.f, ak = 0.f, av = 0.f;
        for (int c = 0; c < DIM; ++c) {
            float l = lat[b*DIM + c];
            aq = fmaf(l, w_qs[c*DIM + f], aq);
            ak = fmaf(l, w_kg[c*DIM + f], ak);
            av = fmaf(l, w_vg[c*DIM + f], av);
        }
        vg_out[b*DIM + f] = av;
        qs[b][f] = aq + pe_b[f];
        hgx[b][f] = aq - ak;
        __syncthreads();
        float acc = g_b1[f], acch = g_b1[f];
        for (int c = 0; c < DIM; ++c) {
            float w = g_w1[c*DIM + f];
            acc  = fmaf(qs[b][c], w, acc);
            acch = fmaf(hgx[b][c], w, acch);
        }
        c1_out[b*DIM + f] = acc;
        h1gx[b][f] = fmaxf(acch, 0.f);
        __syncthreads();
        float acc2 = 0.f;                // b2 dropped (softmax-invariant)
        for (int c = 0; c < DIM; ++c) acc2 = fmaf(h1gx[b][c], g_w2[c*DIM + f], acc2);
        h2g_out[b*DIM + f] = acc2;
    }
}

// ---------------- pre3: kv_proj || point-scatter || query-scatter.  608 x 256 ----------------
__global__ __launch_bounds__(256) void pre3_k(
    const float* __restrict__ points, const float* __restrict__ Wk1,
    const float* __restrict__ w_vs, const float* __restrict__ pe_b,
    const float* __restrict__ xyz, const float* __restrict__ xyz_q,
    int* __restrict__ cursor, int* __restrict__ qcursor,
    float* __restrict__ K1p, float* __restrict__ Vp,
    float2* __restrict__ sxy, int* __restrict__ sidx,
    float2* __restrict__ qsxy, int* __restrict__ qsidx)
{
    __shared__ __align__(16) float pts[KVROWS*DIM];
    int t = threadIdx.x; int bx = blockIdx.x;
    if (bx < 512) {                      // kv_proj (round-7 exact math)
        int r0 = bx * KVROWS;
        #pragma unroll
        for (int k = 0; k < KVROWS*DIM/256; ++k) {
            int e = t + k*256;
            pts[e] = points[r0*DIM + e];
        }
        __syncthreads();
        int f = t & 127; int mat = t >> 7;
        const float* W = mat ? w_vs : Wk1;
        float* O = mat ? Vp : K1p;
        float addv = mat ? pe_b[f] : 0.f;
        float acc[KVROWS];
        #pragma unroll
        for (int r = 0; r < KVROWS; ++r) acc[r] = 0.f;
        const float4* pts4 = reinterpret_cast<const float4*>(pts);
        for (int c4 = 0; c4 < DIM/4; ++c4) {
            float w0 = W[(c4*4+0)*DIM + f];
            float w1 = W[(c4*4+1)*DIM + f];
            float w2 = W[(c4*4+2)*DIM + f];
            float w3 = W[(c4*4+3)*DIM + f];
            #pragma unroll
            for (int r = 0; r < KVROWS; ++r) {
                float4 p = pts4[r*(DIM/4) + c4];
                acc[r] = fmaf(p.x, w0, acc[r]);
                acc[r] = fmaf(p.y, w1, acc[r]);
                acc[r] = fmaf(p.z, w2, acc[r]);
                acc[r] = fmaf(p.w, w3, acc[r]);
            }
        }
        #pragma unroll
        for (int r = 0; r < KVROWS; ++r) O[(r0 + r)*DIM + f] = acc[r] + addv;
    } else if (bx < 544) {               // point scatter
        int gid = (bx - 512)*256 + t;
        int b = gid >> 12; int n = gid & (NPTS - 1);
        const float* p = xyz + (b*NPTS + n)*3;
        float x = p[0], y = p[1];
        int slot = atomicAdd(&cursor[b*NCELL + cell_of(y)*GRID + cell_of(x)], 1);
        sxy[b*NPTS + slot] = make_float2(x, y);
        sidx[b*NPTS + slot] = n;
    } else {                             // query scatter (64 blocks)
        int gid = (bx - 544)*256 + t;
        int b = gid >> 13; int q = gid & (NQ - 1);
        const float* p = xyz_q + (b*NQ + q)*2;
        float x = p[0], y = p[1];
        int slot = atomicAdd(&qcursor[b*NCELL + cell_of(y)*GRID + cell_of(x)], 1);
        qsxy[b*NQ + slot] = make_float2(x, y);
        qsidx[b*NQ + slot] = q;
    }
}

// ---------------- exact kNN v3: ballot rank-select (no shuffle butterfly) ----------------
// Output set is exact; order is arbitrary (downstream softmax+sum is
// neighbor-order-invariant). Threshold found by binary search on float bits
// (positive f32 is u32-monotone); extraction by ballot-prefix compaction.
__global__ __launch_bounds__(256) void knn_k(
    const float2* __restrict__ qsxy, const float2* __restrict__ sxy,
    const int* __restrict__ sidx, const int* __restrict__ cstart,
    int* __restrict__ knn_out)
{
    __shared__ float cand_d[4][CAP];
    __shared__ int   cand_i[4][CAP];
    int t = threadIdx.x; int wid = t >> 6, lane = t & 63;
    int bx = blockIdx.x; int b = bx >> 11; int q = (bx & 2047)*4 + wid;
    float2 qp = qsxy[b*NQ + q];
    float xq = qp.x, yq = qp.y;
    int cx = cell_of(xq), cy = cell_of(yq);
    const int* cs_b = cstart + b*(NCELL+1);
    float* cd = cand_d[wid]; int* ci = cand_i[wid];
    const float INF = 3.4e38f;
    const float CS = 1.0f/32.0f;
    int* outp = knn_out + (b*NQ + q)*KNN;
    unsigned long long lmask = (1ull << lane) - 1ull;

    for (int R = 2; R < 9; ++R) {
        int x0 = max(cx-R, 0), x1 = min(cx+R, GRID-1);
        int y0 = max(cy-R, 0), y1 = min(cy+R, GRID-1);
        int cnt = 0;
        for (int ry = y0; ry <= y1; ++ry) {
            int s0 = cs_b[ry*GRID + x0];
            int e0 = cs_b[ry*GRID + x1 + 1];
            for (int o = s0 + lane; o < e0; o += 64) {
                float2 p = sxy[b*NPTS + o];
                float dx = __fadd_rn(xq, -p.x);
                float dy = __fadd_rn(yq, -p.y);
                float d = __fadd_rn(__fmul_rn(dx, dx), __fmul_rn(dy, dy));
                int slot = cnt + (o - s0);
                if (slot < CAP) { cd[slot] = d; ci[slot] = o; }
            }
            cnt += e0 - s0;
        }
        asm volatile("s_waitcnt lgkmcnt(0)" ::: "memory");
        __builtin_amdgcn_sched_barrier(0);

        int cc = min(cnt, CAP);
        float dr[6];
        #pragma unroll
        for (int k = 0; k < 6; ++k)
            dr[k] = (lane + k*64 < cc) ? cd[lane + k*64] : INF;

        // binary search on f32 bit space for the 16th-smallest distance.
        // invariant: countLE(lo) < 16 <= countLE(hi); all d < 2.0 (unit square).
        unsigned lo = 0u, hi = 0x40000000u;   // 2.0f
        #pragma unroll 1
        for (int it = 0; it < 32; ++it) {
            if (hi - lo <= 1u) break;
            unsigned mid = (lo + hi) >> 1;
            float pv = __uint_as_float(mid);
            int c = 0;
            #pragma unroll
            for (int k = 0; k < 6; ++k)
                c += __popcll(__ballot(dr[k] <= pv));
            if (c >= KNN) {
                hi = mid;
                if (c == KNN) break;     // pv admits exactly 16 -> done
            } else {
                lo = mid;
            }
        }
        float thr = __uint_as_float(hi);     // thr in [d16, d17)

        // boundary guarantee (conservative: thr >= d16)
        float bl = (x0 > 0)      ? (xq - (float)x0*CS)       : INF;
        float br = (x1 < GRID-1) ? ((float)(x1+1)*CS - xq)   : INF;
        float bb = (y0 > 0)      ? (yq - (float)y0*CS)       : INF;
        float bt = (y1 < GRID-1) ? ((float)(y1+1)*CS - yq)   : INF;
        float safe = fminf(fminf(bl, br), fminf(bb, bt)) - 2e-6f;
        bool whole = (safe > 1e8f);
        bool ok = (cnt >= KNN) && (cnt <= CAP) && (whole || thr <= safe*safe);
        if (ok || R == 8) {
            // extraction: strictly-less first, then equals, capped at 16
            int base = 0;
            #pragma unroll
            for (int k = 0; k < 6; ++k) {
                bool p = dr[k] < thr;
                unsigned long long m = __ballot(p);
                int pos = base + __popcll(m & lmask);
                if (p && pos < KNN) outp[pos] = sidx[b*NPTS + ci[lane + k*64]];
                base += __popcll(m);
            }
            #pragma unroll
            for (int k = 0; k < 6; ++k) {
                bool p = dr[k] == thr;
                unsigned long long m = __ballot(p);
                int pos = base + __popcll(m & lmask);
                if (p && pos < KNN) outp[pos] = sidx[b*NPTS + ci[lane + k*64]];
                base += __popcll(m);
            }
            break;
        }
    }
}

// ---------------- fused MFMA kernel (round-7 core) over SORTED queries + XCD swizzle ----------------
__global__ __launch_bounds__(512, 2) void fuse_k(
    const float2* __restrict__ qsxy, const int* __restrict__ qsidx,
    const float* __restrict__ xyz,
    const float* __restrict__ K1p, const float* __restrict__ Vp,
    const int* __restrict__ knn_idx,
    const float* __restrict__ c1_, const float* __restrict__ vg_,
    const float* __restrict__ h2g_, const float* __restrict__ pw32_,
    const ushort_t* __restrict__ pwf, const ushort_t* __restrict__ w2f,
    float* __restrict__ out)
{
    __shared__ __align__(16) ushort_t w2B[32*512];   // 32 KB
    __shared__ __align__(16) ushort_t h1b[8][2048];  // 32 KB (single bf16, per-wave)

    int t = threadIdx.x, lane = t & 63, wid = t >> 6;
    // bijective XCD swizzle over 512 blocks: each XCD gets a contiguous
    // 64-block (2048 sorted-query) spatial slice -> K1p/Vp slice fits its L2.
    int sid = (blockIdx.x & 7) * 64 + (blockIdx.x >> 3);
    int b = sid >> 8; int qbase = (sid & 255) * 32;

    {   // stage w2 frags once per block (32 KB)
        const int4* s2 = (const int4*)w2f;  int4* d2 = (int4*)w2B;
        #pragma unroll
        for (int i = 0; i < 4; ++i) d2[t + i*512] = s2[t + i*512];
    }
    __syncthreads();

    int c16 = lane & 15, g = lane >> 4, rowbase = g*4;
    ushort_t* hb = h1b[wid];
    const vshort8* pwBv = (const vshort8*)pwf;       // global, L1-resident
    const vshort8* w2Bv = (const vshort8*)w2B;
    const vfloat4 vzero = (vfloat4){0.f, 0.f, 0.f, 0.f};

    // query-invariant hoists (per-lane): 40 regs
    float pw32r[16], c1r[8], hgr[8], vgr[8];
    #pragma unroll
    for (int n = 0; n < 16; ++n) pw32r[n] = pw32_[n*16 + c16];
    #pragma unroll
    for (int n = 0; n < 8; ++n) {
        c1r[n] = c1_[b*128 + n*16 + c16];
        hgr[n] = h2g_[b*128 + n*16 + c16];
        vgr[n] = vg_[b*128 + n*16 + c16];
    }

    #pragma unroll 1
    for (int qi = 0; qi < 4; ++qi) {
        int q = qbase + wid*4 + qi;                  // sorted index
        float2 qp = qsxy[b*NQ + q];
        float xq = qp.x, yq = qp.y;
        int qorig = qsidx[b*NQ + q];
        int idxrow = knn_idx[(b*NQ + q)*KNN + c16];
        const float* p = xyz + (b*NPTS + idxrow)*3;
        float pd0 = xq - p[0], pd1 = yq - p[1], pd2 = p[2];
        int idxr[4];
        #pragma unroll
        for (int r = 0; r < 4; ++r) idxr[r] = __shfl(idxrow, rowbase + r);

        // emb A-fragment in registers: k = g*8 + j
        vshort8 eh;
        int k0 = g*8;
        #pragma unroll
        for (int j = 0; j < 8; ++j) {
            int k = k0 + j;
            float v;
            if (k < 3) {
                v = (k == 0) ? pd0 : (k == 1 ? pd1 : pd2);
            } else {
                int m = k - 3; int fi = m / 6; int rem = m - fi*6;
                int comp = (rem < 3) ? rem : rem - 3;
                float pdc = (comp == 0) ? pd0 : (comp == 1 ? pd1 : pd2);
                float fr = (fi == 0) ? 1.0f : (fi == 1) ? 8.75f : (fi == 2) ? 16.5f
                         : (fi == 3) ? 24.25f : 32.0f;
                float arg = pdc * fr;
                v = (rem < 3) ? __sinf(arg) : __cosf(arg);
            }
            eh[j] = (short)bf16_rne(v);
        }
        float c32 = __cosf(32.0f * pd2);
        float c32r[4];
        #pragma unroll
        for (int r = 0; r < 4; ++r) c32r[r] = __shfl(c32, rowbase + r);

        // K1p gather prefetch (transient: dies at end of pe1 phase)
        float k1v[4][8];
        #pragma unroll
        for (int r = 0; r < 4; ++r) {
            const float* kp = K1p + ((b*NPTS + idxr[r]) << 7) + c16;
            #pragma unroll
            for (int n = 0; n < 8; ++n) k1v[r][n] = kp[n*16];
        }

        // pe1 + h1 epilogue, one n at a time (acc1 live = 4 regs)
        #pragma unroll
        for (int n = 0; n < 8; ++n) {
            vfloat4 a = __builtin_amdgcn_mfma_f32_16x16x32_bf16(
                eh, pwBv[n*64 + lane], vzero, 0, 0, 0);
            int col = n*16 + c16;
            int s = col >> 5;
            int lp = ((col >> 3) & 3) << 4;
            int j = c16 & 7;
            #pragma unroll
            for (int r = 0; r < 4; ++r) {
                float h = c1r[n] - k1v[r][n] + fmaf(c32r[r], pw32r[n], a[r]);
                h = fmaxf(h, 0.f);
                hb[s*512 + (lp | (rowbase + r))*8 + j] = bf16_rne(h);
            }
        }
        asm volatile("s_waitcnt lgkmcnt(0)" ::: "memory");
        __builtin_amdgcn_sched_barrier(0);

        // GEMM2: [16x128]@[128x128], single bf16
        vfloat4 acc2[8];
        #pragma unroll
        for (int n = 0; n < 8; ++n) acc2[n] = vzero;
        #pragma unroll
        for (int s = 0; s < 4; ++s) {
            vshort8 ah = ((const vshort8*)hb)[s*64 + lane];
            #pragma unroll
            for (int n = 0; n < 8; ++n) {
                vshort8 bh = w2Bv[(n*4 + s)*64 + lane];
                acc2[n] = __builtin_amdgcn_mfma_f32_16x16x32_bf16(ah, bh, acc2[n], 0, 0, 0);
            }
        }

        // softmax over 17 slots, pe2 computed per-n, Vp gathers depth-1 pipelined
        const float* vbase[4];
        #pragma unroll
        for (int r = 0; r < 4; ++r) vbase[r] = Vp + ((b*NPTS + idxr[r]) << 7) + c16;
        float vvp[4];
        #pragma unroll
        for (int r = 0; r < 4; ++r) vvp[r] = vbase[r][0];

        #pragma unroll
        for (int n = 0; n < 8; ++n) {
            float vvc[4];
            #pragma unroll
            for (int r = 0; r < 4; ++r) vvc[r] = vvp[r];
            if (n < 7) {
                #pragma unroll
                for (int r = 0; r < 4; ++r) vvp[r] = vbase[r][(n+1)*16];
            }
            vfloat4 ap = __builtin_amdgcn_mfma_f32_16x16x32_bf16(
                eh, pwBv[(8 + n)*64 + lane], vzero, 0, 0, 0);
            #pragma unroll
            for (int r = 0; r < 4; ++r) ap[r] = fmaf(c32r[r], pw32r[8 + n], ap[r]);

            float hg = hgr[n];
            vfloat4 a2 = acc2[n];
            float mx = fmaxf(fmaxf(a2[0], a2[1]), fmaxf(a2[2], a2[3]));
            mx = fmaxf(mx, __shfl_xor(mx, 16));
            mx = fmaxf(mx, __shfl_xor(mx, 32));
            mx = fmaxf(mx, hg);
            float sum = 0.f, num = 0.f;
            #pragma unroll
            for (int r = 0; r < 4; ++r) {
                float ev = __expf(a2[r] - mx);
                float v = vvc[r] + ap[r];
                sum += ev;
                num = fmaf(ev, v, num);
            }
            sum += __shfl_xor(sum, 16); sum += __shfl_xor(sum, 32);
            num += __shfl_xor(num, 16); num += __shfl_xor(num, 32);
            float eg = __expf(hg - mx);
            sum += eg;
            num = fmaf(eg, vgr[n], num);
            if (g == 0) out[(b*NQ + qorig)*128 + n*16 + c16] = num / sum;
        }
        asm volatile("s_waitcnt lgkmcnt(0)" ::: "memory");
        __builtin_amdgcn_sched_barrier(0);
    }
}

extern "C" void kernel_launch(void* const* d_in, const int* in_sizes, int n_in,
                              void* d_out, int out_size, void* d_ws, size_t ws_size,
                              hipStream_t stream) {
    const float* xyz_q  = (const float*)d_in[0];
    const float* lat    = (const float*)d_in[1];
    const float* xyz    = (const float*)d_in[2];
    const float* points = (const float*)d_in[3];
    const float* w_qs   = (const float*)d_in[4];
    const float* w_ks   = (const float*)d_in[5];
    const float* w_vs   = (const float*)d_in[6];
    const float* w_kg   = (const float*)d_in[7];
    const float* w_vg   = (const float*)d_in[8];
    const float* g_w1   = (const float*)d_in[9];
    const float* g_b1   = (const float*)d_in[10];
    const float* g_w2   = (const float*)d_in[11];
    const float* g_b2   = (const float*)d_in[12];  // cancels under softmax
    const float* pe_w   = (const float*)d_in[13];
    const float* pe_b   = (const float*)d_in[14];
    float* out = (float*)d_out;
    (void)g_b2;

    float* ws   = (float*)d_ws;
    float* Vp   = ws;                          // 2*4096*128
    float* K1p  = Vp  + NB*NPTS*DIM;           // 2*4096*128
    float* Wk1  = K1p + NB*NPTS*DIM;           // 128*128
    float* pwc  = Wk1 + DIM*DIM;               // 64*256
    float* c1   = pwc + 64*256;                // 256
    float* vg   = c1  + NB*DIM;                // 256
    float* h2g  = vg  + NB*DIM;                // 256
    int*   knn  = (int*)(h2g + NB*DIM);        // 2*8192*16
    ushort_t* pwf = (ushort_t*)(knn + NB*NQ*KNN);   // 16 KB
    ushort_t* w2f = pwf + 16*64*8;                  // 32 KB
    int* cellcnt  = (int*)(w2f + 32*64*8);          // 2*1024   (zeroed)
    int* qcnt     = cellcnt + NB*NCELL;             // 2*1024   (zeroed, adjacent)
    int* cellstart = qcnt + NB*NCELL;               // 2*1025
    int* cursor    = cellstart + NB*(NCELL+1);      // 2*1024
    int* qstart    = cursor + NB*NCELL;             // 2*1025
    int* qcursor   = qstart + NB*(NCELL+1);         // 2*1024
    int* sidx      = qcursor + NB*NCELL;            // 2*4096
    float2* sxy    = (float2*)(sidx + NB*NPTS);     // 2*4096 float2
    int* qsidx     = (int*)(sxy + NB*NPTS);         // 2*8192
    float2* qsxy   = (float2*)(qsidx + NB*NQ);      // 2*8192 float2

    hipMemsetAsync(cellcnt, 0, 2*NB*NCELL*sizeof(int), stream);  // cellcnt + qcnt
    pre1_k<<<224, 256, 0, stream>>>(w_ks, g_w1, pe_w, xyz, xyz_q,
                                    Wk1, pwc, cellcnt, qcnt);
    pre2_k<<<17, 256, 0, stream>>>(pwc, g_w2, cellcnt, qcnt,
                                   lat, w_qs, w_kg, w_vg, g_w1, g_b1, pe_b,
                                   pwf, w2f, cellstart, cursor, qstart, qcursor,
                                   c1, vg, h2g);
    pre3_k<<<608, 256, 0, stream>>>(points, Wk1, w_vs, pe_b, xyz, xyz_q,
                                    cursor, qcursor, K1p, Vp, sxy, sidx, qsxy, qsidx);
    knn_k<<<NB*NQ/4, 256, 0, stream>>>(qsxy, sxy, sidx, cellstart, knn);
    fuse_k<<<NB*NQ/32, 512, 0, stream>>>(qsxy, qsidx, xyz, K1p, Vp, knn, c1, vg, h2g,
                                         pwc + 32*256, pwf, w2f, out);
}